// Round 1
// baseline (539.941 us; speedup 1.0000x reference)
//
#include <hip/hip_runtime.h>
#include <math.h>

#define D 128
#define TM 64

__device__ __forceinline__ float swish_f(float v, float a, float b) {
  return a * v / (1.0f + expf(-b * v));
}

// ---------------- fused resMLP over a 64-atom tile ----------------
// h = swish(x)@W1^T + b1; h = swish(h)@W2^T + b2; y = x + h; out = swish(y)@Wout^T
__global__ __launch_bounds__(256, 2) void resmlp_kernel(
    const float* __restrict__ xin,
    const float* __restrict__ W1b, const float* __restrict__ b1b,
    const float* __restrict__ W2b, const float* __restrict__ b2b,
    const float* __restrict__ Wob,
    const float* __restrict__ act_a, const float* __restrict__ act_b,
    float* __restrict__ outbase, int branch_off, int n_atoms)
{
  __shared__ float xs[D][TM + 4];   // raw x, transposed [feature][atom]
  __shared__ float ss[D][TM + 4];   // current swish activations, transposed
  __shared__ float wl[16][D + 4];   // weight k-chunk [kk][out_col]

  const int tid = threadIdx.x;
  const int n0 = blockIdx.x * TM;
  const int br = blockIdx.y + branch_off;
  const float* W1 = W1b + (size_t)br * D * D;
  const float* W2 = W2b + (size_t)br * D * D;
  const float* Wo = Wob + (size_t)br * D * D;
  const float* b1 = b1b + br * D;
  const float* b2 = b2b + br * D;
  const float a0 = act_a[br * 3 + 0], bb0 = act_b[br * 3 + 0];
  const float a1 = act_a[br * 3 + 1], bb1 = act_b[br * 3 + 1];
  const float a2 = act_a[br * 3 + 2], bb2 = act_b[br * 3 + 2];
  float* out = outbase + (size_t)blockIdx.y * n_atoms * D;

  for (int idx = tid; idx < TM * D; idx += 256) {
    int nn = idx >> 7, j = idx & 127;
    float v = xin[(size_t)(n0 + nn) * D + j];
    xs[j][nn] = v;
    ss[j][nn] = swish_f(v, a0, bb0);
  }
  __syncthreads();

  const int rg = tid & 15, cg = tid >> 4;
  const int r0 = rg * 4, c0 = cg * 8;
  float acc[4][8];

#define GEMM(Wp)                                                             \
  do {                                                                       \
    _Pragma("unroll") for (int i = 0; i < 4; ++i)                            \
        _Pragma("unroll") for (int j = 0; j < 8; ++j) acc[i][j] = 0.f;       \
    for (int k0 = 0; k0 < D; k0 += 16) {                                     \
      for (int idx = tid; idx < D * 16; idx += 256) {                        \
        int i = idx >> 4, kk = idx & 15;                                     \
        wl[kk][i] = Wp[i * D + k0 + kk];                                     \
      }                                                                      \
      __syncthreads();                                                       \
      _Pragma("unroll") for (int kk = 0; kk < 16; ++kk) {                    \
        float4 sA = *(const float4*)&ss[k0 + kk][r0];                        \
        float4 w0 = *(const float4*)&wl[kk][c0];                             \
        float4 w1 = *(const float4*)&wl[kk][c0 + 4];                         \
        float sa[4] = {sA.x, sA.y, sA.z, sA.w};                              \
        float wa[8] = {w0.x, w0.y, w0.z, w0.w, w1.x, w1.y, w1.z, w1.w};      \
        _Pragma("unroll") for (int i = 0; i < 4; ++i)                        \
            _Pragma("unroll") for (int j = 0; j < 8; ++j)                    \
                acc[i][j] += sa[i] * wa[j];                                  \
      }                                                                      \
      __syncthreads();                                                       \
    }                                                                        \
  } while (0)

  // layer 1
  GEMM(W1);
  {
    float bv[8];
#pragma unroll
    for (int j = 0; j < 8; ++j) bv[j] = b1[c0 + j];
#pragma unroll
    for (int i = 0; i < 4; ++i)
#pragma unroll
      for (int j = 0; j < 8; ++j) {
        float h = acc[i][j] + bv[j];
        ss[c0 + j][r0 + i] = swish_f(h, a1, bb1);
      }
  }
  __syncthreads();

  // layer 2 + residual
  GEMM(W2);
  {
    float bv[8];
#pragma unroll
    for (int j = 0; j < 8; ++j) bv[j] = b2[c0 + j];
#pragma unroll
    for (int i = 0; i < 4; ++i)
#pragma unroll
      for (int j = 0; j < 8; ++j) {
        float y = xs[c0 + j][r0 + i] + acc[i][j] + bv[j];
        ss[c0 + j][r0 + i] = swish_f(y, a2, bb2);
      }
  }
  __syncthreads();

  // output layer
  GEMM(Wo);
#pragma unroll
  for (int i = 0; i < 4; ++i) {
    float* op = out + (size_t)(n0 + r0 + i) * D + c0;
    *(float4*)op = make_float4(acc[i][0], acc[i][1], acc[i][2], acc[i][3]);
    *(float4*)(op + 4) = make_float4(acc[i][4], acc[i][5], acc[i][6], acc[i][7]);
  }
#undef GEMM
}

// ---------------- per-edge geometry: rho[16], harmonics[8] ----------------
__global__ void edge_geom_kernel(const float* __restrict__ xyz,
                                 const int* __restrict__ nbrs,
                                 const float* __restrict__ gamma_p,
                                 float* __restrict__ rho_ws,
                                 float* __restrict__ y_ws, int n_edges)
{
  int e = blockIdx.x * 256 + threadIdx.x;
  if (e >= n_edges) return;
  int s = nbrs[2 * e], dd = nbrs[2 * e + 1];
  float rx = xyz[3 * dd + 0] - xyz[3 * s + 0];
  float ry = xyz[3 * dd + 1] - xyz[3 * s + 1];
  float rz = xyz[3 * dd + 2] - xyz[3 * s + 2];
  float r2 = rx * rx + ry * ry + rz * rz + 3e-15f;  // (c^2+EPS).sum()
  float r = sqrtf(r2);
  float inv = 1.0f / r;
  float ux = rx * inv, uy = ry * inv, uz = rz * inv;
  float gamma = gamma_p[0];
  float xv = expf(-gamma * r);
  float omx = 1.0f - xv;
  float fcut = 0.0f;
  if (r < 5.0f) fcut = expf(-r2 / (25.0f - r2));
  float xp[16], op[16];
  xp[0] = 1.f; op[0] = 1.f;
#pragma unroll
  for (int k = 1; k < 16; ++k) { xp[k] = xp[k - 1] * xv; op[k] = op[k - 1] * omx; }
  const float C[16] = {1.f, 15.f, 105.f, 455.f, 1365.f, 3003.f, 5005.f, 6435.f,
                       6435.f, 5005.f, 3003.f, 1365.f, 455.f, 105.f, 15.f, 1.f};
  float* rp = rho_ws + (size_t)e * 16;
#pragma unroll
  for (int k = 0; k < 16; ++k) rp[k] = C[k] * xp[k] * op[15 - k] * fcut;
  const float s3 = 1.7320508075688772f;
  float* yp = y_ws + (size_t)e * 8;
  yp[0] = uy; yp[1] = uz; yp[2] = ux;
  yp[3] = s3 * ux * uy; yp[4] = s3 * uy * uz; yp[5] = 0.5f * (3.f * uz * uz - 1.f);
  yp[6] = s3 * ux * uz; yp[7] = 0.5f * s3 * (ux * ux - uy * uy);
}

// ---------------- CSR build: histogram, scan, scatter ----------------
__global__ void hist_kernel(const int* __restrict__ nbrs, int* __restrict__ counts, int n_edges) {
  int e = blockIdx.x * 256 + threadIdx.x;
  if (e < n_edges) atomicAdd(&counts[nbrs[2 * e]], 1);
}

__global__ __launch_bounds__(1024) void scan_kernel(const int* __restrict__ counts,
                                                    int* __restrict__ offsets, int n) {
  __shared__ int part[1024];
  int tid = threadIdx.x;
  int base = tid * 16;
  int loc[16]; int s = 0;
#pragma unroll
  for (int i = 0; i < 16; ++i) {
    int c = (base + i < n) ? counts[base + i] : 0;
    loc[i] = c; s += c;
  }
  part[tid] = s;
  __syncthreads();
  for (int off = 1; off < 1024; off <<= 1) {
    int v = (tid >= off) ? part[tid - off] : 0;
    __syncthreads();
    part[tid] += v;
    __syncthreads();
  }
  int run = (tid == 0) ? 0 : part[tid - 1];
#pragma unroll
  for (int i = 0; i < 16; ++i) {
    if (base + i < n) offsets[base + i] = run;
    run += loc[i];
  }
}

__global__ void scatter_kernel(const int* __restrict__ nbrs, const int* __restrict__ offsets,
                               int* __restrict__ cursor, int* __restrict__ sorted, int n_edges) {
  int e = blockIdx.x * 256 + threadIdx.x;
  if (e < n_edges) {
    int s = nbrs[2 * e];
    int pos = offsets[s] + atomicAdd(&cursor[s], 1);
    sorted[pos] = e;
  }
}

// ---------------- per-atom aggregation (segment sum, no float atomics) ----------------
__global__ __launch_bounds__(128) void aggregate_kernel(
    const float* __restrict__ rho_ws, const float* __restrict__ y_ws,
    const int* __restrict__ nbrs, const int* __restrict__ offsets,
    const int* __restrict__ counts, const int* __restrict__ sorted,
    const float* __restrict__ feat1, const float* __restrict__ feat2,
    const float* __restrict__ feat3,
    const float* __restrict__ Gs, const float* __restrict__ Gp,
    const float* __restrict__ Gd,
    float* __restrict__ q0, float* __restrict__ q1, float* __restrict__ q2,
    int n_atoms)
{
  int n = blockIdx.x;
  int d = threadIdx.x;
  float gs[16], gp[16], gd[16];
#pragma unroll
  for (int c = 0; c < 4; ++c) {
    float4 v = *(const float4*)&Gs[d * 16 + 4 * c];
    gs[4 * c] = v.x; gs[4 * c + 1] = v.y; gs[4 * c + 2] = v.z; gs[4 * c + 3] = v.w;
    v = *(const float4*)&Gp[d * 16 + 4 * c];
    gp[4 * c] = v.x; gp[4 * c + 1] = v.y; gp[4 * c + 2] = v.z; gp[4 * c + 3] = v.w;
    v = *(const float4*)&Gd[d * 16 + 4 * c];
    gd[4 * c] = v.x; gd[4 * c + 1] = v.y; gd[4 * c + 2] = v.z; gd[4 * c + 3] = v.w;
  }
  float a0 = 0.f, a1[3] = {0.f, 0.f, 0.f}, a2[5] = {0.f, 0.f, 0.f, 0.f, 0.f};
  int off = offsets[n], cnt = counts[n];
  for (int i = 0; i < cnt; ++i) {
    int e = sorted[off + i];
    int dst = nbrs[2 * e + 1];
    const float4* rp = (const float4*)(rho_ws + (size_t)e * 16);
    float4 r0v = rp[0], r1v = rp[1], r2v = rp[2], r3v = rp[3];
    float rho[16] = {r0v.x, r0v.y, r0v.z, r0v.w, r1v.x, r1v.y, r1v.z, r1v.w,
                     r2v.x, r2v.y, r2v.z, r2v.w, r3v.x, r3v.y, r3v.z, r3v.w};
    const float4* ypv = (const float4*)(y_ws + (size_t)e * 8);
    float4 y0v = ypv[0], y1v = ypv[1];
    float g_s = 0.f, g_p = 0.f, g_d = 0.f;
#pragma unroll
    for (int k = 0; k < 16; ++k) {
      g_s += gs[k] * rho[k];
      g_p += gp[k] * rho[k];
      g_d += gd[k] * rho[k];
    }
    float f1 = feat1[(size_t)dst * D + d];
    float f2 = feat2[(size_t)dst * D + d];
    float f3 = feat3[(size_t)dst * D + d];
    a0 += f1 * g_s;
    float ap = f2 * g_p;
    a1[0] += ap * y0v.x; a1[1] += ap * y0v.y; a1[2] += ap * y0v.z;
    float ad = f3 * g_d;
    a2[0] += ad * y0v.w; a2[1] += ad * y1v.x; a2[2] += ad * y1v.y;
    a2[3] += ad * y1v.z; a2[4] += ad * y1v.w;
  }
  q0[(size_t)n * D + d] = a0;
#pragma unroll
  for (int m = 0; m < 3; ++m) q1[((size_t)m * n_atoms + n) * D + d] = a1[m];
#pragma unroll
  for (int m = 0; m < 5; ++m) q2[((size_t)m * n_atoms + n) * D + d] = a2[m];
}

// ---------------- take_inner for P (m=3) and D (m=5) + assemble inp ----------------
__global__ __launch_bounds__(256, 2) void inner_kernel(
    const float* __restrict__ q1, const float* __restrict__ q2,
    const float* __restrict__ P1, const float* __restrict__ P2,
    const float* __restrict__ D1m, const float* __restrict__ D2m,
    const float* __restrict__ cterm, const float* __restrict__ q0,
    float* __restrict__ inp, int n_atoms)
{
  __shared__ float qs[D][TM + 4];
  __shared__ float wlA[16][D + 4];
  __shared__ float wlB[16][D + 4];
  const int tid = threadIdx.x;
  const int n0 = blockIdx.x * TM;
  const int rg = tid & 15, cg = tid >> 4;
  const int r0 = rg * 4, c0 = cg * 8;
  float eacc[4][8];
#pragma unroll
  for (int i = 0; i < 4; ++i)
#pragma unroll
    for (int j = 0; j < 8; ++j) eacc[i][j] = 0.f;

  for (int part = 0; part < 8; ++part) {
    const float* qp; const float* M1; const float* M2;
    if (part < 3) { qp = q1 + (size_t)part * n_atoms * D; M1 = P1; M2 = P2; }
    else          { qp = q2 + (size_t)(part - 3) * n_atoms * D; M1 = D1m; M2 = D2m; }
    __syncthreads();
    for (int idx = tid; idx < TM * D; idx += 256) {
      int nn = idx >> 7, j = idx & 127;
      qs[j][nn] = qp[(size_t)(n0 + nn) * D + j];
    }
    __syncthreads();
    float t1[4][8], t2[4][8];
#pragma unroll
    for (int i = 0; i < 4; ++i)
#pragma unroll
      for (int j = 0; j < 8; ++j) { t1[i][j] = 0.f; t2[i][j] = 0.f; }
    for (int k0 = 0; k0 < D; k0 += 16) {
      for (int idx = tid; idx < D * 16; idx += 256) {
        int i = idx >> 4, kk = idx & 15;
        wlA[kk][i] = M1[i * D + k0 + kk];
        wlB[kk][i] = M2[i * D + k0 + kk];
      }
      __syncthreads();
#pragma unroll
      for (int kk = 0; kk < 16; ++kk) {
        float4 sA = *(const float4*)&qs[k0 + kk][r0];
        float4 a0v = *(const float4*)&wlA[kk][c0];
        float4 a1v = *(const float4*)&wlA[kk][c0 + 4];
        float4 b0v = *(const float4*)&wlB[kk][c0];
        float4 b1v = *(const float4*)&wlB[kk][c0 + 4];
        float sa[4] = {sA.x, sA.y, sA.z, sA.w};
        float wa[8] = {a0v.x, a0v.y, a0v.z, a0v.w, a1v.x, a1v.y, a1v.z, a1v.w};
        float wb[8] = {b0v.x, b0v.y, b0v.z, b0v.w, b1v.x, b1v.y, b1v.z, b1v.w};
#pragma unroll
        for (int i = 0; i < 4; ++i)
#pragma unroll
          for (int j = 0; j < 8; ++j) {
            t1[i][j] += sa[i] * wa[j];
            t2[i][j] += sa[i] * wb[j];
          }
      }
      __syncthreads();
    }
#pragma unroll
    for (int i = 0; i < 4; ++i)
#pragma unroll
      for (int j = 0; j < 8; ++j) eacc[i][j] += t1[i][j] * t2[i][j];
  }

#pragma unroll
  for (int i = 0; i < 4; ++i) {
    size_t row = (size_t)(n0 + r0 + i) * D + c0;
    float4 cA = *(const float4*)&cterm[row];
    float4 cB = *(const float4*)&cterm[row + 4];
    float4 zA = *(const float4*)&q0[row];
    float4 zB = *(const float4*)&q0[row + 4];
    *(float4*)&inp[row] = make_float4(eacc[i][0] + cA.x + zA.x, eacc[i][1] + cA.y + zA.y,
                                      eacc[i][2] + cA.z + zA.z, eacc[i][3] + cA.w + zA.w);
    *(float4*)&inp[row + 4] = make_float4(eacc[i][4] + cB.x + zB.x, eacc[i][5] + cB.y + zB.y,
                                          eacc[i][6] + cB.z + zB.z, eacc[i][7] + cB.w + zB.w);
  }
}

extern "C" void kernel_launch(void* const* d_in, const int* in_sizes, int n_in,
                              void* d_out, int out_size, void* d_ws, size_t ws_size,
                              hipStream_t stream)
{
  const float* xyz     = (const float*)d_in[0];
  const float* x_tilde = (const float*)d_in[1];
  const int*   nbrs    = (const int*)d_in[2];
  const float* W1      = (const float*)d_in[3];
  const float* b1      = (const float*)d_in[4];
  const float* W2      = (const float*)d_in[5];
  const float* b2      = (const float*)d_in[6];
  const float* Wout    = (const float*)d_in[7];
  const float* act_a   = (const float*)d_in[8];
  const float* act_b   = (const float*)d_in[9];
  const float* Gs      = (const float*)d_in[10];
  const float* Gp      = (const float*)d_in[11];
  const float* Gd      = (const float*)d_in[12];
  const float* P1      = (const float*)d_in[13];
  const float* P2      = (const float*)d_in[14];
  const float* D1m     = (const float*)d_in[15];
  const float* D2m     = (const float*)d_in[16];
  const float* gamma   = (const float*)d_in[17];
  float* out = (float*)d_out;

  const int n_atoms = in_sizes[0] / 3;   // 16384
  const int n_edges = in_sizes[2] / 2;   // 100000

  // workspace layout (floats)
  float* ws = (float*)d_ws;
  size_t nd = (size_t)n_atoms * D;
  float* feats  = ws;                       // 4*nd: c_term, feat1..3
  float* q0     = feats + 4 * nd;           // nd
  float* q1     = q0 + nd;                  // 3*nd
  float* q2     = q1 + 3 * nd;              // 5*nd
  float* rho_ws = q2 + 5 * nd;              // E*16
  float* y_ws   = rho_ws + (size_t)n_edges * 16;  // E*8
  float* inp    = y_ws + (size_t)n_edges * 8;     // nd
  int* counts  = (int*)(inp + nd);
  int* offsets = counts + n_atoms;
  int* cursor  = offsets + n_atoms;
  int* sorted  = cursor + n_atoms;          // E ints

  hipMemsetAsync(counts, 0, (size_t)n_atoms * sizeof(int), stream);
  hipMemsetAsync(cursor, 0, (size_t)n_atoms * sizeof(int), stream);

  dim3 blk(256);
  int eb = (n_edges + 255) / 256;

  // branches 0..3 on x_tilde -> feats[branch]
  resmlp_kernel<<<dim3(n_atoms / TM, 4), blk, 0, stream>>>(
      x_tilde, W1, b1, W2, b2, Wout, act_a, act_b, feats, 0, n_atoms);

  edge_geom_kernel<<<eb, blk, 0, stream>>>(xyz, nbrs, gamma, rho_ws, y_ws, n_edges);
  hist_kernel<<<eb, blk, 0, stream>>>(nbrs, counts, n_edges);
  scan_kernel<<<1, 1024, 0, stream>>>(counts, offsets, n_atoms);
  scatter_kernel<<<eb, blk, 0, stream>>>(nbrs, offsets, cursor, sorted, n_edges);

  aggregate_kernel<<<n_atoms, 128, 0, stream>>>(
      rho_ws, y_ws, nbrs, offsets, counts, sorted,
      feats + nd, feats + 2 * nd, feats + 3 * nd, Gs, Gp, Gd,
      q0, q1, q2, n_atoms);

  inner_kernel<<<n_atoms / TM, blk, 0, stream>>>(
      q1, q2, P1, P2, D1m, D2m, feats, q0, inp, n_atoms);

  // branch 4 on inp -> out
  resmlp_kernel<<<dim3(n_atoms / TM, 1), blk, 0, stream>>>(
      inp, W1, b1, W2, b2, Wout, act_a, act_b, out, 4, n_atoms);
}

// Round 3
// 501.837 us; speedup vs baseline: 1.0759x; 1.0759x over previous
//
#include <hip/hip_runtime.h>
#include <math.h>

#define D 128

__device__ __forceinline__ float swish_f(float v, float a, float b) {
  return a * v / (1.0f + expf(-b * v));
}

// ---------------- fused resMLP over a TMT-atom tile ----------------
// h = swish(x)@W1^T + b1; h = swish(h)@W2^T + b2; y = x + h; out = swish(y)@Wout^T
template <int TMT>
__global__ __launch_bounds__(256, 2) void resmlp_kernel(
    const float* __restrict__ xin,
    const float* __restrict__ W1b, const float* __restrict__ b1b,
    const float* __restrict__ W2b, const float* __restrict__ b2b,
    const float* __restrict__ Wob,
    const float* __restrict__ act_a, const float* __restrict__ act_b,
    float* __restrict__ outbase, int branch_off, int n_atoms)
{
  constexpr int RT = TMT / 16;       // rows per thread
  __shared__ float xs[D][TMT + 4];   // raw x, transposed [feature][atom]
  __shared__ float ss[D][TMT + 4];   // current swish activations, transposed
  __shared__ float wl[16][D + 4];    // weight k-chunk [kk][out_col]

  const int tid = threadIdx.x;
  const int n0 = blockIdx.x * TMT;
  const int br = blockIdx.y + branch_off;
  const float* W1 = W1b + (size_t)br * D * D;
  const float* W2 = W2b + (size_t)br * D * D;
  const float* Wo = Wob + (size_t)br * D * D;
  const float* b1 = b1b + br * D;
  const float* b2 = b2b + br * D;
  const float a0 = act_a[br * 3 + 0], bb0 = act_b[br * 3 + 0];
  const float a1 = act_a[br * 3 + 1], bb1 = act_b[br * 3 + 1];
  const float a2 = act_a[br * 3 + 2], bb2 = act_b[br * 3 + 2];
  float* out = outbase + (size_t)blockIdx.y * n_atoms * D;

  for (int idx = tid; idx < TMT * D; idx += 256) {
    int nn = idx >> 7, j = idx & 127;
    float v = xin[(size_t)(n0 + nn) * D + j];
    xs[j][nn] = v;
    ss[j][nn] = swish_f(v, a0, bb0);
  }
  __syncthreads();

  const int rg = tid & 15, cg = tid >> 4;
  const int r0 = rg * RT, c0 = cg * 8;
  float acc[RT][8];

#define GEMM(Wp)                                                             \
  do {                                                                       \
    _Pragma("unroll") for (int i = 0; i < RT; ++i)                           \
        _Pragma("unroll") for (int j = 0; j < 8; ++j) acc[i][j] = 0.f;       \
    for (int k0 = 0; k0 < D; k0 += 16) {                                     \
      for (int idx = tid; idx < D * 16; idx += 256) {                        \
        int i = idx >> 4, kk = idx & 15;                                     \
        wl[kk][i] = Wp[i * D + k0 + kk];                                     \
      }                                                                      \
      __syncthreads();                                                       \
      _Pragma("unroll") for (int kk = 0; kk < 16; ++kk) {                    \
        float sa[RT];                                                        \
        _Pragma("unroll") for (int i = 0; i < RT; ++i)                       \
            sa[i] = ss[k0 + kk][r0 + i];                                     \
        float4 w0 = *(const float4*)&wl[kk][c0];                             \
        float4 w1 = *(const float4*)&wl[kk][c0 + 4];                         \
        float wa[8] = {w0.x, w0.y, w0.z, w0.w, w1.x, w1.y, w1.z, w1.w};      \
        _Pragma("unroll") for (int i = 0; i < RT; ++i)                       \
            _Pragma("unroll") for (int j = 0; j < 8; ++j)                    \
                acc[i][j] += sa[i] * wa[j];                                  \
      }                                                                      \
      __syncthreads();                                                       \
    }                                                                        \
  } while (0)

  // layer 1
  GEMM(W1);
  {
    float bv[8];
#pragma unroll
    for (int j = 0; j < 8; ++j) bv[j] = b1[c0 + j];
#pragma unroll
    for (int i = 0; i < RT; ++i)
#pragma unroll
      for (int j = 0; j < 8; ++j) {
        float h = acc[i][j] + bv[j];
        ss[c0 + j][r0 + i] = swish_f(h, a1, bb1);
      }
  }
  __syncthreads();

  // layer 2 + residual
  GEMM(W2);
  {
    float bv[8];
#pragma unroll
    for (int j = 0; j < 8; ++j) bv[j] = b2[c0 + j];
#pragma unroll
    for (int i = 0; i < RT; ++i)
#pragma unroll
      for (int j = 0; j < 8; ++j) {
        float y = xs[c0 + j][r0 + i] + acc[i][j] + bv[j];
        ss[c0 + j][r0 + i] = swish_f(y, a2, bb2);
      }
  }
  __syncthreads();

  // output layer
  GEMM(Wo);
#pragma unroll
  for (int i = 0; i < RT; ++i) {
    float* op = out + (size_t)(n0 + r0 + i) * D + c0;
    *(float4*)op = make_float4(acc[i][0], acc[i][1], acc[i][2], acc[i][3]);
    *(float4*)(op + 4) = make_float4(acc[i][4], acc[i][5], acc[i][6], acc[i][7]);
  }
#undef GEMM
}

// ---------------- per-edge geometry: rho[16], harmonics[8] ----------------
__global__ void edge_geom_kernel(const float* __restrict__ xyz,
                                 const int* __restrict__ nbrs,
                                 const float* __restrict__ gamma_p,
                                 float* __restrict__ rho_ws,
                                 float* __restrict__ y_ws, int n_edges)
{
  int e = blockIdx.x * 256 + threadIdx.x;
  if (e >= n_edges) return;
  int s = nbrs[2 * e], dd = nbrs[2 * e + 1];
  float rx = xyz[3 * dd + 0] - xyz[3 * s + 0];
  float ry = xyz[3 * dd + 1] - xyz[3 * s + 1];
  float rz = xyz[3 * dd + 2] - xyz[3 * s + 2];
  float r2 = rx * rx + ry * ry + rz * rz + 3e-15f;  // (c^2+EPS).sum()
  float r = sqrtf(r2);
  float inv = 1.0f / r;
  float ux = rx * inv, uy = ry * inv, uz = rz * inv;
  float gamma = gamma_p[0];
  float xv = expf(-gamma * r);
  float omx = 1.0f - xv;
  float fcut = 0.0f;
  if (r < 5.0f) fcut = expf(-r2 / (25.0f - r2));
  float xp[16], op[16];
  xp[0] = 1.f; op[0] = 1.f;
#pragma unroll
  for (int k = 1; k < 16; ++k) { xp[k] = xp[k - 1] * xv; op[k] = op[k - 1] * omx; }
  const float C[16] = {1.f, 15.f, 105.f, 455.f, 1365.f, 3003.f, 5005.f, 6435.f,
                       6435.f, 5005.f, 3003.f, 1365.f, 455.f, 105.f, 15.f, 1.f};
  float* rp = rho_ws + (size_t)e * 16;
#pragma unroll
  for (int k = 0; k < 16; ++k) rp[k] = C[k] * xp[k] * op[15 - k] * fcut;
  const float s3 = 1.7320508075688772f;
  float* yp = y_ws + (size_t)e * 8;
  yp[0] = uy; yp[1] = uz; yp[2] = ux;
  yp[3] = s3 * ux * uy; yp[4] = s3 * uy * uz; yp[5] = 0.5f * (3.f * uz * uz - 1.f);
  yp[6] = s3 * ux * uz; yp[7] = 0.5f * s3 * (ux * ux - uy * uy);
}

// ---------------- CSR build: histogram, scan, scatter ----------------
__global__ void hist_kernel(const int* __restrict__ nbrs, int* __restrict__ counts, int n_edges) {
  int e = blockIdx.x * 256 + threadIdx.x;
  if (e < n_edges) atomicAdd(&counts[nbrs[2 * e]], 1);
}

__global__ __launch_bounds__(1024) void scan_kernel(const int* __restrict__ counts,
                                                    int* __restrict__ offsets, int n) {
  __shared__ int part[1024];
  int tid = threadIdx.x;
  int base = tid * 16;
  int loc[16]; int s = 0;
#pragma unroll
  for (int i = 0; i < 16; ++i) {
    int c = (base + i < n) ? counts[base + i] : 0;
    loc[i] = c; s += c;
  }
  part[tid] = s;
  __syncthreads();
  for (int off = 1; off < 1024; off <<= 1) {
    int v = (tid >= off) ? part[tid - off] : 0;
    __syncthreads();
    part[tid] += v;
    __syncthreads();
  }
  int run = (tid == 0) ? 0 : part[tid - 1];
#pragma unroll
  for (int i = 0; i < 16; ++i) {
    if (base + i < n) offsets[base + i] = run;
    run += loc[i];
  }
}

__global__ void scatter_kernel(const int* __restrict__ nbrs, const int* __restrict__ offsets,
                               int* __restrict__ cursor, int* __restrict__ sorted, int n_edges) {
  int e = blockIdx.x * 256 + threadIdx.x;
  if (e < n_edges) {
    int s = nbrs[2 * e];
    int pos = offsets[s] + atomicAdd(&cursor[s], 1);
    sorted[pos] = e;
  }
}

// ---------------- per-atom aggregation (segment sum, no float atomics) ----------------
__global__ __launch_bounds__(128) void aggregate_kernel(
    const float* __restrict__ rho_ws, const float* __restrict__ y_ws,
    const int* __restrict__ nbrs, const int* __restrict__ offsets,
    const int* __restrict__ counts, const int* __restrict__ sorted,
    const float* __restrict__ feat1, const float* __restrict__ feat2,
    const float* __restrict__ feat3,
    const float* __restrict__ Gs, const float* __restrict__ Gp,
    const float* __restrict__ Gd,
    float* __restrict__ q0, float* __restrict__ q1, float* __restrict__ q2,
    int n_atoms)
{
  int n = blockIdx.x;
  int d = threadIdx.x;
  float gs[16], gp[16], gd[16];
#pragma unroll
  for (int c = 0; c < 4; ++c) {
    float4 v = *(const float4*)&Gs[d * 16 + 4 * c];
    gs[4 * c] = v.x; gs[4 * c + 1] = v.y; gs[4 * c + 2] = v.z; gs[4 * c + 3] = v.w;
    v = *(const float4*)&Gp[d * 16 + 4 * c];
    gp[4 * c] = v.x; gp[4 * c + 1] = v.y; gp[4 * c + 2] = v.z; gp[4 * c + 3] = v.w;
    v = *(const float4*)&Gd[d * 16 + 4 * c];
    gd[4 * c] = v.x; gd[4 * c + 1] = v.y; gd[4 * c + 2] = v.z; gd[4 * c + 3] = v.w;
  }
  float a0 = 0.f, a1[3] = {0.f, 0.f, 0.f}, a2[5] = {0.f, 0.f, 0.f, 0.f, 0.f};
  int off = offsets[n], cnt = counts[n];
  for (int i = 0; i < cnt; ++i) {
    int e = sorted[off + i];
    int dst = nbrs[2 * e + 1];
    const float4* rp = (const float4*)(rho_ws + (size_t)e * 16);
    float4 r0v = rp[0], r1v = rp[1], r2v = rp[2], r3v = rp[3];
    float rho[16] = {r0v.x, r0v.y, r0v.z, r0v.w, r1v.x, r1v.y, r1v.z, r1v.w,
                     r2v.x, r2v.y, r2v.z, r2v.w, r3v.x, r3v.y, r3v.z, r3v.w};
    const float4* ypv = (const float4*)(y_ws + (size_t)e * 8);
    float4 y0v = ypv[0], y1v = ypv[1];
    float g_s = 0.f, g_p = 0.f, g_d = 0.f;
#pragma unroll
    for (int k = 0; k < 16; ++k) {
      g_s += gs[k] * rho[k];
      g_p += gp[k] * rho[k];
      g_d += gd[k] * rho[k];
    }
    float f1 = feat1[(size_t)dst * D + d];
    float f2 = feat2[(size_t)dst * D + d];
    float f3 = feat3[(size_t)dst * D + d];
    a0 += f1 * g_s;
    float ap = f2 * g_p;
    a1[0] += ap * y0v.x; a1[1] += ap * y0v.y; a1[2] += ap * y0v.z;
    float ad = f3 * g_d;
    a2[0] += ad * y0v.w; a2[1] += ad * y1v.x; a2[2] += ad * y1v.y;
    a2[3] += ad * y1v.z; a2[4] += ad * y1v.w;
  }
  q0[(size_t)n * D + d] = a0;
#pragma unroll
  for (int m = 0; m < 3; ++m) q1[((size_t)m * n_atoms + n) * D + d] = a1[m];
#pragma unroll
  for (int m = 0; m < 5; ++m) q2[((size_t)m * n_atoms + n) * D + d] = a2[m];
}

// ---------------- take_inner, split over part-groups ----------------
// blockIdx.y = g (0..3); handles parts 2g and 2g+1 of the 8 (3 P-parts, 5 D-parts).
// Writes eacc = sum over its 2 parts of t1*t2 into partial[g] (plain stores).
__global__ __launch_bounds__(256, 2) void inner_part_kernel(
    const float* __restrict__ q1, const float* __restrict__ q2,
    const float* __restrict__ P1, const float* __restrict__ P2,
    const float* __restrict__ D1m, const float* __restrict__ D2m,
    float* __restrict__ pA, float* __restrict__ pB, int n_atoms)
{
  const int TM = 64;
  __shared__ float qs[D][TM + 4];
  __shared__ float wlA[16][D + 4];
  __shared__ float wlB[16][D + 4];
  const int tid = threadIdx.x;
  const int n0 = blockIdx.x * TM;
  const int g = blockIdx.y;
  const size_t nd = (size_t)n_atoms * D;
  const int rg = tid & 15, cg = tid >> 4;
  const int r0 = rg * 4, c0 = cg * 8;
  float eacc[4][8];
#pragma unroll
  for (int i = 0; i < 4; ++i)
#pragma unroll
    for (int j = 0; j < 8; ++j) eacc[i][j] = 0.f;

  for (int pp = 0; pp < 2; ++pp) {
    const int part = 2 * g + pp;
    const float* qp; const float* M1; const float* M2;
    if (part < 3) { qp = q1 + (size_t)part * nd; M1 = P1; M2 = P2; }
    else          { qp = q2 + (size_t)(part - 3) * nd; M1 = D1m; M2 = D2m; }
    __syncthreads();
    for (int idx = tid; idx < TM * D; idx += 256) {
      int nn = idx >> 7, j = idx & 127;
      qs[j][nn] = qp[(size_t)(n0 + nn) * D + j];
    }
    __syncthreads();
    float t1[4][8], t2[4][8];
#pragma unroll
    for (int i = 0; i < 4; ++i)
#pragma unroll
      for (int j = 0; j < 8; ++j) { t1[i][j] = 0.f; t2[i][j] = 0.f; }
    for (int k0 = 0; k0 < D; k0 += 16) {
      for (int idx = tid; idx < D * 16; idx += 256) {
        int i = idx >> 4, kk = idx & 15;
        wlA[kk][i] = M1[i * D + k0 + kk];
        wlB[kk][i] = M2[i * D + k0 + kk];
      }
      __syncthreads();
#pragma unroll
      for (int kk = 0; kk < 16; ++kk) {
        float4 sA = *(const float4*)&qs[k0 + kk][r0];
        float4 a0v = *(const float4*)&wlA[kk][c0];
        float4 a1v = *(const float4*)&wlA[kk][c0 + 4];
        float4 b0v = *(const float4*)&wlB[kk][c0];
        float4 b1v = *(const float4*)&wlB[kk][c0 + 4];
        float sa[4] = {sA.x, sA.y, sA.z, sA.w};
        float wa[8] = {a0v.x, a0v.y, a0v.z, a0v.w, a1v.x, a1v.y, a1v.z, a1v.w};
        float wb[8] = {b0v.x, b0v.y, b0v.z, b0v.w, b1v.x, b1v.y, b1v.z, b1v.w};
#pragma unroll
        for (int i = 0; i < 4; ++i)
#pragma unroll
          for (int j = 0; j < 8; ++j) {
            t1[i][j] += sa[i] * wa[j];
            t2[i][j] += sa[i] * wb[j];
          }
      }
      __syncthreads();
    }
#pragma unroll
    for (int i = 0; i < 4; ++i)
#pragma unroll
      for (int j = 0; j < 8; ++j) eacc[i][j] += t1[i][j] * t2[i][j];
  }

  float* outp = (g < 3) ? (pA + (size_t)g * nd) : pB;
#pragma unroll
  for (int i = 0; i < 4; ++i) {
    float* op = outp + (size_t)(n0 + r0 + i) * D + c0;
    *(float4*)op = make_float4(eacc[i][0], eacc[i][1], eacc[i][2], eacc[i][3]);
    *(float4*)(op + 4) = make_float4(eacc[i][4], eacc[i][5], eacc[i][6], eacc[i][7]);
  }
}

// ---------------- assemble: inp = cterm + q0 + sum of 4 partials ----------------
__global__ void assemble_kernel(const float* __restrict__ cterm,
                                const float* __restrict__ q0,
                                const float* __restrict__ pA,
                                const float* __restrict__ pB,
                                float* __restrict__ inp, int nd4)
{
  int i = blockIdx.x * 256 + threadIdx.x;
  if (i >= nd4) return;
  const float4* c = (const float4*)cterm;
  const float4* z = (const float4*)q0;
  const float4* a = (const float4*)pA;
  const float4* b = (const float4*)pB;
  float4 v = c[i], zz = z[i];
  float4 a0 = a[i], a1 = a[i + (size_t)nd4], a2 = a[i + 2 * (size_t)nd4], bb = b[i];
  float4 r;
  r.x = v.x + zz.x + a0.x + a1.x + a2.x + bb.x;
  r.y = v.y + zz.y + a0.y + a1.y + a2.y + bb.y;
  r.z = v.z + zz.z + a0.z + a1.z + a2.z + bb.z;
  r.w = v.w + zz.w + a0.w + a1.w + a2.w + bb.w;
  ((float4*)inp)[i] = r;
}

extern "C" void kernel_launch(void* const* d_in, const int* in_sizes, int n_in,
                              void* d_out, int out_size, void* d_ws, size_t ws_size,
                              hipStream_t stream)
{
  const float* xyz     = (const float*)d_in[0];
  const float* x_tilde = (const float*)d_in[1];
  const int*   nbrs    = (const int*)d_in[2];
  const float* W1      = (const float*)d_in[3];
  const float* b1      = (const float*)d_in[4];
  const float* W2      = (const float*)d_in[5];
  const float* b2      = (const float*)d_in[6];
  const float* Wout    = (const float*)d_in[7];
  const float* act_a   = (const float*)d_in[8];
  const float* act_b   = (const float*)d_in[9];
  const float* Gs      = (const float*)d_in[10];
  const float* Gp      = (const float*)d_in[11];
  const float* Gd      = (const float*)d_in[12];
  const float* P1      = (const float*)d_in[13];
  const float* P2      = (const float*)d_in[14];
  const float* D1m     = (const float*)d_in[15];
  const float* D2m     = (const float*)d_in[16];
  const float* gamma   = (const float*)d_in[17];
  float* out = (float*)d_out;

  const int n_atoms = in_sizes[0] / 3;   // 16384
  const int n_edges = in_sizes[2] / 2;   // 100000

  // workspace layout (floats)
  float* ws = (float*)d_ws;
  size_t nd = (size_t)n_atoms * D;
  float* feats  = ws;                       // 4*nd: c_term, feat1..3
  float* q0     = feats + 4 * nd;           // nd
  float* q1     = q0 + nd;                  // 3*nd
  float* q2     = q1 + 3 * nd;              // 5*nd
  float* rho_ws = q2 + 5 * nd;              // E*16  (dead after aggregate -> partial B)
  float* y_ws   = rho_ws + (size_t)n_edges * 16;  // E*8
  float* inp    = y_ws + (size_t)n_edges * 8;     // nd
  int* counts  = (int*)(inp + nd);
  int* offsets = counts + n_atoms;
  int* cursor  = offsets + n_atoms;
  int* sorted  = cursor + n_atoms;          // E ints

  // partials: reuse feat1..3 (dead after aggregate) for groups 0..2,
  // group 3 uses rho_ws+y_ws region (dead after aggregate; E*24 = 2.4M floats >= nd). OK.
  float* pA = feats + nd;
  float* pB = rho_ws;

  hipMemsetAsync(counts, 0, (size_t)n_atoms * sizeof(int), stream);
  hipMemsetAsync(cursor, 0, (size_t)n_atoms * sizeof(int), stream);

  dim3 blk(256);
  int eb = (n_edges + 255) / 256;

  // branches 0..3 on x_tilde -> feats[branch]  (TM=32: 512x4 = 2048 blocks)
  resmlp_kernel<32><<<dim3(n_atoms / 32, 4), blk, 0, stream>>>(
      x_tilde, W1, b1, W2, b2, Wout, act_a, act_b, feats, 0, n_atoms);

  edge_geom_kernel<<<eb, blk, 0, stream>>>(xyz, nbrs, gamma, rho_ws, y_ws, n_edges);
  hist_kernel<<<eb, blk, 0, stream>>>(nbrs, counts, n_edges);
  scan_kernel<<<1, 1024, 0, stream>>>(counts, offsets, n_atoms);
  scatter_kernel<<<eb, blk, 0, stream>>>(nbrs, offsets, cursor, sorted, n_edges);

  aggregate_kernel<<<n_atoms, 128, 0, stream>>>(
      rho_ws, y_ws, nbrs, offsets, counts, sorted,
      feats + nd, feats + 2 * nd, feats + 3 * nd, Gs, Gp, Gd,
      q0, q1, q2, n_atoms);

  // take_inner split over 4 part-groups (256x4 = 1024 blocks)
  inner_part_kernel<<<dim3(n_atoms / 64, 4), blk, 0, stream>>>(
      q1, q2, P1, P2, D1m, D2m, pA, pB, n_atoms);

  assemble_kernel<<<(int)((nd / 4 + 255) / 256), blk, 0, stream>>>(
      feats, q0, pA, pB, inp, (int)(nd / 4));

  // branch 4 on inp -> out  (TM=16: 1024 blocks)
  resmlp_kernel<16><<<dim3(n_atoms / 16, 1), blk, 0, stream>>>(
      inp, W1, b1, W2, b2, Wout, act_a, act_b, out, 4, n_atoms);
}

// Round 5
// 356.530 us; speedup vs baseline: 1.5144x; 1.4076x over previous
//
#include <hip/hip_runtime.h>
#include <math.h>

#define D 128

typedef __attribute__((ext_vector_type(8))) short short8v;   // 8 bf16 (4 VGPR)
typedef __attribute__((ext_vector_type(4))) float f32x4;      // MFMA acc
typedef __attribute__((ext_vector_type(4))) unsigned int uint4v;

__device__ __forceinline__ float swish_f(float v, float a, float b) {
  return a * v / (1.0f + expf(-b * v));
}

// round-to-nearest-even split: v ~= hi + lo (each bf16), error ~2^-17 rel
__device__ __forceinline__ void bf16split(float v, unsigned short& h, unsigned short& l) {
  unsigned int u = __float_as_uint(v);
  unsigned int rh = (u + 0x7FFFu + ((u >> 16) & 1u)) & 0xFFFF0000u;
  h = (unsigned short)(rh >> 16);
  float lf = v - __uint_as_float(rh);
  unsigned int u2 = __float_as_uint(lf);
  unsigned int rl = u2 + 0x7FFFu + ((u2 >> 16) & 1u);
  l = (unsigned short)(rl >> 16);
}

// ---- stage a 16x128 f32 tile into XOR-swizzled hi/lo bf16 LDS (1 wave) ----
// swizzle: within-row byte offset ^= ((row&7)<<4)  (G4 fix for D=128 row-major)
template <bool SW>
__device__ __forceinline__ void stage16(const float* __restrict__ src, int lane,
                                        unsigned short* shHi, unsigned short* shLo,
                                        float a, float b) {
#pragma unroll
  for (int i = 0; i < 4; ++i) {
    int t = lane + 64 * i;
    int r = t >> 4, c = t & 15;          // row, 8-float chunk
    const float4 v0 = *(const float4*)(src + r * D + c * 8);
    const float4 v1 = *(const float4*)(src + r * D + c * 8 + 4);
    float vv[8] = {v0.x, v0.y, v0.z, v0.w, v1.x, v1.y, v1.z, v1.w};
    unsigned int hw[4], lw[4];
#pragma unroll
    for (int jj = 0; jj < 4; ++jj) {
      float x0 = SW ? swish_f(vv[2 * jj], a, b) : vv[2 * jj];
      float x1 = SW ? swish_f(vv[2 * jj + 1], a, b) : vv[2 * jj + 1];
      unsigned short h0, l0, h1, l1;
      bf16split(x0, h0, l0);
      bf16split(x1, h1, l1);
      hw[jj] = (unsigned int)h0 | ((unsigned int)h1 << 16);
      lw[jj] = (unsigned int)l0 | ((unsigned int)l1 << 16);
    }
    int off = (c * 16) ^ ((r & 7) << 4);
    uint4v hv = {hw[0], hw[1], hw[2], hw[3]};
    uint4v lv = {lw[0], lw[1], lw[2], lw[3]};
    *(uint4v*)((char*)(shHi + r * D) + off) = hv;
    *(uint4v*)((char*)(shLo + r * D) + off) = lv;
  }
}

// A-frag: lane holds row (lane&15), k = kc*32 + (lane>>4)*8 + j
__device__ __forceinline__ void load_afrags(const unsigned short* sh, int lane, short8v* f) {
  int rl = lane & 15, q = lane >> 4;
  const char* base = (const char*)(sh + rl * D);
#pragma unroll
  for (int kc = 0; kc < 4; ++kc) {
    int off = (kc * 64 + q * 16) ^ ((rl & 7) << 4);
    f[kc] = *(const short8v*)(base + off);
  }
}

// C = X @ W^T over 16x128x128 with bf16x2 split (3 MFMAs per frag pair)
__device__ __forceinline__ void gemm16(const short8v* ah, const short8v* al,
                                       const unsigned short* __restrict__ prep, int m,
                                       int lane, f32x4* accs) {
  const short8v* ph = (const short8v*)(prep + (size_t)(2 * m) * 16384);
  const short8v* pl = (const short8v*)(prep + (size_t)(2 * m + 1) * 16384);
#pragma unroll
  for (int nt = 0; nt < 8; ++nt) {
    f32x4 acc = {0.f, 0.f, 0.f, 0.f};
#pragma unroll
    for (int kc = 0; kc < 4; ++kc) {
      int ci = (nt * 4 + kc) * 64 + lane;
      short8v bh = ph[ci];
      short8v bl = pl[ci];
      acc = __builtin_amdgcn_mfma_f32_16x16x32_bf16(al[kc], bh, acc, 0, 0, 0);
      acc = __builtin_amdgcn_mfma_f32_16x16x32_bf16(ah[kc], bl, acc, 0, 0, 0);
      acc = __builtin_amdgcn_mfma_f32_16x16x32_bf16(ah[kc], bh, acc, 0, 0, 0);
    }
    accs[nt] = acc;
  }
}

// ---- prep: 19 [128x128] f32 matrices -> fragment-major bf16 hi/lo planes ----
// m: 0-4 W1[br], 5-9 W2[br], 10-14 Wout[br], 15 P1, 16 P2, 17 D1, 18 D2
// chunk layout per matrix-plane: [nt(8)][kc(4)][lane(64)] x 8 bf16, so a wave's
// B-frag load (ph[ci], ci=(nt*4+kc)*64+lane) is 1KB fully-coalesced.
__global__ void prep_weights_kernel(const float* __restrict__ W1, const float* __restrict__ W2,
                                    const float* __restrict__ Wo, const float* __restrict__ P1,
                                    const float* __restrict__ P2, const float* __restrict__ D1,
                                    const float* __restrict__ D2, unsigned short* __restrict__ prep) {
  int t = blockIdx.x * 256 + threadIdx.x;
  if (t >= 19 * 2048) return;
  int m = t >> 11;
  int rem = t & 2047;
  int nt = rem >> 8;
  int kc = (rem >> 6) & 3;
  int lane = rem & 63;
  const float* src;
  if (m < 5) src = W1 + (size_t)m * 16384;
  else if (m < 10) src = W2 + (size_t)(m - 5) * 16384;
  else if (m < 15) src = Wo + (size_t)(m - 10) * 16384;
  else if (m == 15) src = P1;
  else if (m == 16) src = P2;
  else if (m == 17) src = D1;
  else src = D2;
  int row = nt * 16 + (lane & 15);            // N index
  int k0 = kc * 32 + (lane >> 4) * 8;         // K index
  unsigned int hw[4], lw[4];
#pragma unroll
  for (int jj = 0; jj < 4; ++jj) {
    unsigned short h0, l0, h1, l1;
    bf16split(src[row * D + k0 + 2 * jj], h0, l0);
    bf16split(src[row * D + k0 + 2 * jj + 1], h1, l1);
    hw[jj] = (unsigned int)h0 | ((unsigned int)h1 << 16);
    lw[jj] = (unsigned int)l0 | ((unsigned int)l1 << 16);
  }
  size_t chunk = (size_t)((nt * 4 + kc) * 64 + lane);
  uint4v hv = {hw[0], hw[1], hw[2], hw[3]};
  uint4v lv = {lw[0], lw[1], lw[2], lw[3]};
  *(uint4v*)(prep + (size_t)(2 * m) * 16384 + chunk * 8) = hv;
  *(uint4v*)(prep + (size_t)(2 * m + 1) * 16384 + chunk * 8) = lv;
}

// ---------------- resMLP via MFMA: 1 wave per 16-atom tile, 0 barriers ----------------
__global__ __launch_bounds__(64) void resmlp_mfma(
    const float* __restrict__ xin, const unsigned short* __restrict__ prep,
    const float* __restrict__ b1b, const float* __restrict__ b2b,
    const float* __restrict__ act_a, const float* __restrict__ act_b,
    float* __restrict__ outbase, int branch_off, int n_atoms)
{
  __shared__ __align__(16) unsigned short shHi[16 * D];
  __shared__ __align__(16) unsigned short shLo[16 * D];
  const int lane = threadIdx.x;
  const int atom0 = blockIdx.x * 16;
  const int br = blockIdx.y + branch_off;
  const float* b1 = b1b + br * D;
  const float* b2 = b2b + br * D;
  const float a0 = act_a[br * 3 + 0], g0 = act_b[br * 3 + 0];
  const float a1 = act_a[br * 3 + 1], g1 = act_b[br * 3 + 1];
  const float a2 = act_a[br * 3 + 2], g2 = act_b[br * 3 + 2];
  float* out = outbase + (size_t)blockIdx.y * n_atoms * D;
  const float* x0 = xin + (size_t)atom0 * D;

  stage16<true>(x0, lane, shHi, shLo, a0, g0);   // s0 = swish(x0)

  const int rl = lane & 15;
  const int rowq = (lane >> 4) * 4;
  short8v ah[4], al[4];
  f32x4 accs[8];

  // layer 1: h = s0 @ W1^T + b1; s1 = swish(h)
  load_afrags(shHi, lane, ah);
  load_afrags(shLo, lane, al);
  gemm16(ah, al, prep, br, lane, accs);
#pragma unroll
  for (int nt = 0; nt < 8; ++nt) {
    int col = nt * 16 + rl;
    float bv = b1[col];
#pragma unroll
    for (int r = 0; r < 4; ++r) {
      int row = rowq + r;
      float s = swish_f(accs[nt][r] + bv, a1, g1);
      unsigned short h, l;
      bf16split(s, h, l);
      int off = (col * 2) ^ ((row & 7) << 4);
      *(unsigned short*)((char*)(shHi + row * D) + off) = h;
      *(unsigned short*)((char*)(shLo + row * D) + off) = l;
    }
  }

  // layer 2: y = x0 + s1 @ W2^T + b2; s2 = swish(y)
  load_afrags(shHi, lane, ah);
  load_afrags(shLo, lane, al);
  gemm16(ah, al, prep, 5 + br, lane, accs);
#pragma unroll
  for (int nt = 0; nt < 8; ++nt) {
    int col = nt * 16 + rl;
    float bv = b2[col];
#pragma unroll
    for (int r = 0; r < 4; ++r) {
      int row = rowq + r;
      float y = x0[row * D + col] + accs[nt][r] + bv;   // residual re-read (L2)
      float s = swish_f(y, a2, g2);
      unsigned short h, l;
      bf16split(s, h, l);
      int off = (col * 2) ^ ((row & 7) << 4);
      *(unsigned short*)((char*)(shHi + row * D) + off) = h;
      *(unsigned short*)((char*)(shLo + row * D) + off) = l;
    }
  }

  // layer 3: out = s2 @ Wo^T
  load_afrags(shHi, lane, ah);
  load_afrags(shLo, lane, al);
  gemm16(ah, al, prep, 10 + br, lane, accs);
#pragma unroll
  for (int nt = 0; nt < 8; ++nt)
#pragma unroll
    for (int r = 0; r < 4; ++r)
      out[(size_t)(atom0 + rowq + r) * D + nt * 16 + rl] = accs[nt][r];
}

// ---------------- take_inner via MFMA: t1 = q_m @ M1^T, t2 = q_m @ M2^T, eacc += t1*t2 ----
__global__ __launch_bounds__(64) void inner_mfma(
    const float* __restrict__ q1, const float* __restrict__ q2,
    const unsigned short* __restrict__ prep,
    float* __restrict__ pA, float* __restrict__ pB, int n_atoms)
{
  __shared__ __align__(16) unsigned short shHi[16 * D];
  __shared__ __align__(16) unsigned short shLo[16 * D];
  const int lane = threadIdx.x;
  const int atom0 = blockIdx.x * 16;
  const int g = blockIdx.y;
  const size_t nd = (size_t)n_atoms * D;
  const int rl = lane & 15;
  const int rowq = (lane >> 4) * 4;
  f32x4 eacc[8];
#pragma unroll
  for (int nt = 0; nt < 8; ++nt) eacc[nt] = f32x4{0.f, 0.f, 0.f, 0.f};

  for (int pp = 0; pp < 2; ++pp) {
    const int part = g * 2 + pp;
    const float* qp = (part < 3) ? q1 + (size_t)part * nd : q2 + (size_t)(part - 3) * nd;
    const int m1 = (part < 3) ? 15 : 17;     // P1/P2 or D1/D2
    stage16<false>(qp + (size_t)atom0 * D, lane, shHi, shLo, 0.f, 0.f);
    short8v ah[4], al[4];
    load_afrags(shHi, lane, ah);
    load_afrags(shLo, lane, al);
    const short8v* p1h = (const short8v*)(prep + (size_t)(2 * m1) * 16384);
    const short8v* p1l = (const short8v*)(prep + (size_t)(2 * m1 + 1) * 16384);
    const short8v* p2h = (const short8v*)(prep + (size_t)(2 * m1 + 2) * 16384);
    const short8v* p2l = (const short8v*)(prep + (size_t)(2 * m1 + 3) * 16384);
#pragma unroll
    for (int nt = 0; nt < 8; ++nt) {
      f32x4 t1 = {0.f, 0.f, 0.f, 0.f}, t2 = {0.f, 0.f, 0.f, 0.f};
#pragma unroll
      for (int kc = 0; kc < 4; ++kc) {
        int ci = (nt * 4 + kc) * 64 + lane;
        short8v b1h = p1h[ci], b1l = p1l[ci];
        short8v b2h = p2h[ci], b2l = p2l[ci];
        t1 = __builtin_amdgcn_mfma_f32_16x16x32_bf16(al[kc], b1h, t1, 0, 0, 0);
        t1 = __builtin_amdgcn_mfma_f32_16x16x32_bf16(ah[kc], b1l, t1, 0, 0, 0);
        t1 = __builtin_amdgcn_mfma_f32_16x16x32_bf16(ah[kc], b1h, t1, 0, 0, 0);
        t2 = __builtin_amdgcn_mfma_f32_16x16x32_bf16(al[kc], b2h, t2, 0, 0, 0);
        t2 = __builtin_amdgcn_mfma_f32_16x16x32_bf16(ah[kc], b2l, t2, 0, 0, 0);
        t2 = __builtin_amdgcn_mfma_f32_16x16x32_bf16(ah[kc], b2h, t2, 0, 0, 0);
      }
      eacc[nt] += t1 * t2;
    }
  }
  float* outp = (g < 3) ? (pA + (size_t)g * nd) : pB;
#pragma unroll
  for (int nt = 0; nt < 8; ++nt)
#pragma unroll
    for (int r = 0; r < 4; ++r)
      outp[(size_t)(atom0 + rowq + r) * D + nt * 16 + rl] = eacc[nt][r];
}

// ---------------- per-edge geometry: rho[16], harmonics[8] ----------------
__global__ void edge_geom_kernel(const float* __restrict__ xyz,
                                 const int* __restrict__ nbrs,
                                 const float* __restrict__ gamma_p,
                                 float* __restrict__ rho_ws,
                                 float* __restrict__ y_ws, int n_edges)
{
  int e = blockIdx.x * 256 + threadIdx.x;
  if (e >= n_edges) return;
  int s = nbrs[2 * e], dd = nbrs[2 * e + 1];
  float rx = xyz[3 * dd + 0] - xyz[3 * s + 0];
  float ry = xyz[3 * dd + 1] - xyz[3 * s + 1];
  float rz = xyz[3 * dd + 2] - xyz[3 * s + 2];
  float r2 = rx * rx + ry * ry + rz * rz + 3e-15f;
  float r = sqrtf(r2);
  float inv = 1.0f / r;
  float ux = rx * inv, uy = ry * inv, uz = rz * inv;
  float gamma = gamma_p[0];
  float xv = expf(-gamma * r);
  float omx = 1.0f - xv;
  float fcut = 0.0f;
  if (r < 5.0f) fcut = expf(-r2 / (25.0f - r2));
  float xp[16], op[16];
  xp[0] = 1.f; op[0] = 1.f;
#pragma unroll
  for (int k = 1; k < 16; ++k) { xp[k] = xp[k - 1] * xv; op[k] = op[k - 1] * omx; }
  const float C[16] = {1.f, 15.f, 105.f, 455.f, 1365.f, 3003.f, 5005.f, 6435.f,
                       6435.f, 5005.f, 3003.f, 1365.f, 455.f, 105.f, 15.f, 1.f};
  float* rp = rho_ws + (size_t)e * 16;
#pragma unroll
  for (int k = 0; k < 16; ++k) rp[k] = C[k] * xp[k] * op[15 - k] * fcut;
  const float s3 = 1.7320508075688772f;
  float* yp = y_ws + (size_t)e * 8;
  yp[0] = uy; yp[1] = uz; yp[2] = ux;
  yp[3] = s3 * ux * uy; yp[4] = s3 * uy * uz; yp[5] = 0.5f * (3.f * uz * uz - 1.f);
  yp[6] = s3 * ux * uz; yp[7] = 0.5f * s3 * (ux * ux - uy * uy);
}

// ---------------- CSR build: histogram, scan, scatter ----------------
__global__ void hist_kernel(const int* __restrict__ nbrs, int* __restrict__ counts, int n_edges) {
  int e = blockIdx.x * 256 + threadIdx.x;
  if (e < n_edges) atomicAdd(&counts[nbrs[2 * e]], 1);
}

__global__ __launch_bounds__(1024) void scan_kernel(const int* __restrict__ counts,
                                                    int* __restrict__ offsets, int n) {
  __shared__ int part[1024];
  int tid = threadIdx.x;
  int base = tid * 16;
  int loc[16]; int s = 0;
#pragma unroll
  for (int i = 0; i < 16; ++i) {
    int c = (base + i < n) ? counts[base + i] : 0;
    loc[i] = c; s += c;
  }
  part[tid] = s;
  __syncthreads();
  for (int off = 1; off < 1024; off <<= 1) {
    int v = (tid >= off) ? part[tid - off] : 0;
    __syncthreads();
    part[tid] += v;
    __syncthreads();
  }
  int run = (tid == 0) ? 0 : part[tid - 1];
#pragma unroll
  for (int i = 0; i < 16; ++i) {
    if (base + i < n) offsets[base + i] = run;
    run += loc[i];
  }
}

__global__ void scatter_kernel(const int* __restrict__ nbrs, const int* __restrict__ offsets,
                               int* __restrict__ cursor, int* __restrict__ sorted, int n_edges) {
  int e = blockIdx.x * 256 + threadIdx.x;
  if (e < n_edges) {
    int s = nbrs[2 * e];
    int pos = offsets[s] + atomicAdd(&cursor[s], 1);
    sorted[pos] = e;
  }
}

// ---------------- per-atom aggregation (segment sum, no float atomics) ----------------
__global__ __launch_bounds__(128) void aggregate_kernel(
    const float* __restrict__ rho_ws, const float* __restrict__ y_ws,
    const int* __restrict__ nbrs, const int* __restrict__ offsets,
    const int* __restrict__ counts, const int* __restrict__ sorted,
    const float* __restrict__ feat1, const float* __restrict__ feat2,
    const float* __restrict__ feat3,
    const float* __restrict__ Gs, const float* __restrict__ Gp,
    const float* __restrict__ Gd,
    float* __restrict__ q0, float* __restrict__ q1, float* __restrict__ q2,
    int n_atoms)
{
  int n = blockIdx.x;
  int d = threadIdx.x;
  float gs[16], gp[16], gd[16];
#pragma unroll
  for (int c = 0; c < 4; ++c) {
    float4 v = *(const float4*)&Gs[d * 16 + 4 * c];
    gs[4 * c] = v.x; gs[4 * c + 1] = v.y; gs[4 * c + 2] = v.z; gs[4 * c + 3] = v.w;
    v = *(const float4*)&Gp[d * 16 + 4 * c];
    gp[4 * c] = v.x; gp[4 * c + 1] = v.y; gp[4 * c + 2] = v.z; gp[4 * c + 3] = v.w;
    v = *(const float4*)&Gd[d * 16 + 4 * c];
    gd[4 * c] = v.x; gd[4 * c + 1] = v.y; gd[4 * c + 2] = v.z; gd[4 * c + 3] = v.w;
  }
  float a0 = 0.f, a1[3] = {0.f, 0.f, 0.f}, a2[5] = {0.f, 0.f, 0.f, 0.f, 0.f};
  int off = offsets[n], cnt = counts[n];
  for (int i = 0; i < cnt; ++i) {
    int e = sorted[off + i];
    int dst = nbrs[2 * e + 1];
    const float4* rp = (const float4*)(rho_ws + (size_t)e * 16);
    float4 r0v = rp[0], r1v = rp[1], r2v = rp[2], r3v = rp[3];
    float rho[16] = {r0v.x, r0v.y, r0v.z, r0v.w, r1v.x, r1v.y, r1v.z, r1v.w,
                     r2v.x, r2v.y, r2v.z, r2v.w, r3v.x, r3v.y, r3v.z, r3v.w};
    const float4* ypv = (const float4*)(y_ws + (size_t)e * 8);
    float4 y0v = ypv[0], y1v = ypv[1];
    float g_s = 0.f, g_p = 0.f, g_d = 0.f;
#pragma unroll
    for (int k = 0; k < 16; ++k) {
      g_s += gs[k] * rho[k];
      g_p += gp[k] * rho[k];
      g_d += gd[k] * rho[k];
    }
    float f1 = feat1[(size_t)dst * D + d];
    float f2 = feat2[(size_t)dst * D + d];
    float f3 = feat3[(size_t)dst * D + d];
    a0 += f1 * g_s;
    float ap = f2 * g_p;
    a1[0] += ap * y0v.x; a1[1] += ap * y0v.y; a1[2] += ap * y0v.z;
    float ad = f3 * g_d;
    a2[0] += ad * y0v.w; a2[1] += ad * y1v.x; a2[2] += ad * y1v.y;
    a2[3] += ad * y1v.z; a2[4] += ad * y1v.w;
  }
  q0[(size_t)n * D + d] = a0;
#pragma unroll
  for (int m = 0; m < 3; ++m) q1[((size_t)m * n_atoms + n) * D + d] = a1[m];
#pragma unroll
  for (int m = 0; m < 5; ++m) q2[((size_t)m * n_atoms + n) * D + d] = a2[m];
}

// ---------------- assemble: inp = cterm + q0 + sum of 4 partials ----------------
__global__ void assemble_kernel(const float* __restrict__ cterm,
                                const float* __restrict__ q0,
                                const float* __restrict__ pA,
                                const float* __restrict__ pB,
                                float* __restrict__ inp, int nd4)
{
  int i = blockIdx.x * 256 + threadIdx.x;
  if (i >= nd4) return;
  const float4* c = (const float4*)cterm;
  const float4* z = (const float4*)q0;
  const float4* a = (const float4*)pA;
  const float4* b = (const float4*)pB;
  float4 v = c[i], zz = z[i];
  float4 a0 = a[i], a1 = a[i + (size_t)nd4], a2 = a[i + 2 * (size_t)nd4], bb = b[i];
  float4 r;
  r.x = v.x + zz.x + a0.x + a1.x + a2.x + bb.x;
  r.y = v.y + zz.y + a0.y + a1.y + a2.y + bb.y;
  r.z = v.z + zz.z + a0.z + a1.z + a2.z + bb.z;
  r.w = v.w + zz.w + a0.w + a1.w + a2.w + bb.w;
  ((float4*)inp)[i] = r;
}

extern "C" void kernel_launch(void* const* d_in, const int* in_sizes, int n_in,
                              void* d_out, int out_size, void* d_ws, size_t ws_size,
                              hipStream_t stream)
{
  const float* xyz     = (const float*)d_in[0];
  const float* x_tilde = (const float*)d_in[1];
  const int*   nbrs    = (const int*)d_in[2];
  const float* W1      = (const float*)d_in[3];
  const float* b1      = (const float*)d_in[4];
  const float* W2      = (const float*)d_in[5];
  const float* b2      = (const float*)d_in[6];
  const float* Wout    = (const float*)d_in[7];
  const float* act_a   = (const float*)d_in[8];
  const float* act_b   = (const float*)d_in[9];
  const float* Gs      = (const float*)d_in[10];
  const float* Gp      = (const float*)d_in[11];
  const float* Gd      = (const float*)d_in[12];
  const float* P1      = (const float*)d_in[13];
  const float* P2      = (const float*)d_in[14];
  const float* D1m     = (const float*)d_in[15];
  const float* D2m     = (const float*)d_in[16];
  const float* gamma   = (const float*)d_in[17];
  float* out = (float*)d_out;

  const int n_atoms = in_sizes[0] / 3;   // 16384
  const int n_edges = in_sizes[2] / 2;   // 100000

  // workspace layout (floats)
  float* ws = (float*)d_ws;
  size_t nd = (size_t)n_atoms * D;
  float* feats  = ws;                       // 4*nd: c_term, feat1..3
  float* q0     = feats + 4 * nd;           // nd
  float* q1     = q0 + nd;                  // 3*nd
  float* q2     = q1 + 3 * nd;              // 5*nd
  float* rho_ws = q2 + 5 * nd;              // E*16 (dead after aggregate -> partial B)
  float* y_ws   = rho_ws + (size_t)n_edges * 16;  // E*8
  float* inp    = y_ws + (size_t)n_edges * 8;     // nd
  int* counts  = (int*)(inp + nd);
  int* offsets = counts + n_atoms;
  int* cursor  = offsets + n_atoms;
  int* sorted  = cursor + n_atoms;          // E ints
  // prepped weights: 19 matrices x (hi,lo) x 16384 bf16 = 1.19 MB, 16B-aligned
  unsigned short* prep =
      (unsigned short*)(((uintptr_t)(sorted + n_edges) + 15) & ~(uintptr_t)15);

  // partials: reuse feat1..3 (dead after aggregate) for groups 0..2,
  // group 3 uses rho_ws+y_ws region (dead after aggregate; E*24 >= nd). OK.
  float* pA = feats + nd;
  float* pB = rho_ws;

  hipMemsetAsync(counts, 0, (size_t)n_atoms * sizeof(int), stream);
  hipMemsetAsync(cursor, 0, (size_t)n_atoms * sizeof(int), stream);

  dim3 blk(256);
  int eb = (n_edges + 255) / 256;

  prep_weights_kernel<<<(19 * 2048 + 255) / 256, blk, 0, stream>>>(
      W1, W2, Wout, P1, P2, D1m, D2m, prep);

  // branches 0..3 on x_tilde -> feats[branch]  (1024 x 4 single-wave blocks)
  resmlp_mfma<<<dim3(n_atoms / 16, 4), dim3(64), 0, stream>>>(
      x_tilde, prep, b1, b2, act_a, act_b, feats, 0, n_atoms);

  edge_geom_kernel<<<eb, blk, 0, stream>>>(xyz, nbrs, gamma, rho_ws, y_ws, n_edges);
  hist_kernel<<<eb, blk, 0, stream>>>(nbrs, counts, n_edges);
  scan_kernel<<<1, 1024, 0, stream>>>(counts, offsets, n_atoms);
  scatter_kernel<<<eb, blk, 0, stream>>>(nbrs, offsets, cursor, sorted, n_edges);

  aggregate_kernel<<<n_atoms, 128, 0, stream>>>(
      rho_ws, y_ws, nbrs, offsets, counts, sorted,
      feats + nd, feats + 2 * nd, feats + 3 * nd, Gs, Gp, Gd,
      q0, q1, q2, n_atoms);

  // take_inner split over 4 part-groups (1024 x 4 single-wave blocks)
  inner_mfma<<<dim3(n_atoms / 16, 4), dim3(64), 0, stream>>>(
      q1, q2, prep, pA, pB, n_atoms);

  assemble_kernel<<<(int)((nd / 4 + 255) / 256), blk, 0, stream>>>(
      feats, q0, pA, pB, inp, (int)(nd / 4));

  // branch 4 on inp -> out (1024 single-wave blocks)
  resmlp_mfma<<<dim3(n_atoms / 16, 1), dim3(64), 0, stream>>>(
      inp, prep, b1, b2, act_a, act_b, out, 4, n_atoms);
}

// Round 6
// 340.297 us; speedup vs baseline: 1.5867x; 1.0477x over previous
//
#include <hip/hip_runtime.h>
#include <math.h>

#define D 128

typedef __attribute__((ext_vector_type(8))) short short8v;   // 8 bf16 (4 VGPR)
typedef __attribute__((ext_vector_type(4))) float f32x4;      // MFMA acc
typedef __attribute__((ext_vector_type(4))) unsigned int uint4v;

// fast swish: a*x*sigmoid(b*x), exp2+rcp form (~6 VALU insts, rel err <2^-21)
__device__ __forceinline__ float fast_swish(float v, float a, float b) {
  float e = __builtin_amdgcn_exp2f(-1.4426950408889634f * (b * v));
  return a * v * __builtin_amdgcn_rcpf(1.0f + e);
}

// exact RNE split (prep only): v ~= hi + lo, err ~2^-18
__device__ __forceinline__ void bf16split_rne(float v, unsigned short& h, unsigned short& l) {
  unsigned int u = __float_as_uint(v);
  unsigned int rh = (u + 0x7FFFu + ((u >> 16) & 1u)) & 0xFFFF0000u;
  h = (unsigned short)(rh >> 16);
  float lf = v - __uint_as_float(rh);
  unsigned int u2 = __float_as_uint(lf);
  unsigned int rl = u2 + 0x7FFFu + ((u2 >> 16) & 1u);
  l = (unsigned short)(rl >> 16);
}

// fast split (hot path): truncate hi, RNE lo; reconstruction err ~2^-17
__device__ __forceinline__ void bf16split_fast(float v, unsigned short& h, unsigned short& l) {
  unsigned int u = __float_as_uint(v);
  h = (unsigned short)(u >> 16);
  float lf = v - __uint_as_float(u & 0xFFFF0000u);
  unsigned int u2 = __float_as_uint(lf);
  l = (unsigned short)((u2 + 0x7FFFu + ((u2 >> 16) & 1u)) >> 16);
}

// ---- stage a 16x128 f32 tile into XOR-swizzled hi/lo bf16 LDS (1 wave) ----
// swizzle: within-row byte offset ^= ((row&7)<<4)  (G4 fix for D=128 row-major)
template <bool SW>
__device__ __forceinline__ void stage16(const float* __restrict__ src, int lane,
                                        unsigned short* shHi, unsigned short* shLo,
                                        float a, float b) {
#pragma unroll
  for (int i = 0; i < 4; ++i) {
    int t = lane + 64 * i;
    int r = t >> 4, c = t & 15;          // row, 8-float chunk
    const float4 v0 = *(const float4*)(src + r * D + c * 8);
    const float4 v1 = *(const float4*)(src + r * D + c * 8 + 4);
    float vv[8] = {v0.x, v0.y, v0.z, v0.w, v1.x, v1.y, v1.z, v1.w};
    unsigned int hw[4], lw[4];
#pragma unroll
    for (int jj = 0; jj < 4; ++jj) {
      float x0 = SW ? fast_swish(vv[2 * jj], a, b) : vv[2 * jj];
      float x1 = SW ? fast_swish(vv[2 * jj + 1], a, b) : vv[2 * jj + 1];
      unsigned short h0, l0, h1, l1;
      bf16split_fast(x0, h0, l0);
      bf16split_fast(x1, h1, l1);
      hw[jj] = (unsigned int)h0 | ((unsigned int)h1 << 16);
      lw[jj] = (unsigned int)l0 | ((unsigned int)l1 << 16);
    }
    int off = (c * 16) ^ ((r & 7) << 4);
    uint4v hv = {hw[0], hw[1], hw[2], hw[3]};
    uint4v lv = {lw[0], lw[1], lw[2], lw[3]};
    *(uint4v*)((char*)(shHi + r * D) + off) = hv;
    *(uint4v*)((char*)(shLo + r * D) + off) = lv;
  }
}

// A-frag: lane holds row (lane&15), k = kc*32 + (lane>>4)*8 + j
__device__ __forceinline__ void load_afrags(const unsigned short* sh, int lane, short8v* f) {
  int rl = lane & 15, q = lane >> 4;
  const char* base = (const char*)(sh + rl * D);
#pragma unroll
  for (int kc = 0; kc < 4; ++kc) {
    int off = (kc * 64 + q * 16) ^ ((rl & 7) << 4);
    f[kc] = *(const short8v*)(base + off);
  }
}

// C = X @ W^T over 16x128x128 with bf16x2 split (3 MFMAs per frag pair)
__device__ __forceinline__ void gemm16(const short8v* ah, const short8v* al,
                                       const unsigned short* __restrict__ prep, int m,
                                       int lane, f32x4* accs) {
  const short8v* ph = (const short8v*)(prep + (size_t)(2 * m) * 16384);
  const short8v* pl = (const short8v*)(prep + (size_t)(2 * m + 1) * 16384);
#pragma unroll
  for (int nt = 0; nt < 8; ++nt) {
    f32x4 acc = {0.f, 0.f, 0.f, 0.f};
#pragma unroll
    for (int kc = 0; kc < 4; ++kc) {
      int ci = (nt * 4 + kc) * 64 + lane;
      short8v bh = ph[ci];
      short8v bl = pl[ci];
      acc = __builtin_amdgcn_mfma_f32_16x16x32_bf16(al[kc], bh, acc, 0, 0, 0);
      acc = __builtin_amdgcn_mfma_f32_16x16x32_bf16(ah[kc], bl, acc, 0, 0, 0);
      acc = __builtin_amdgcn_mfma_f32_16x16x32_bf16(ah[kc], bh, acc, 0, 0, 0);
    }
    accs[nt] = acc;
  }
}

// ---- prep: 19 [128x128] f32 matrices -> fragment-major bf16 hi/lo planes ----
// m: 0-4 W1[br], 5-9 W2[br], 10-14 Wout[br], 15 P1, 16 P2, 17 D1, 18 D2
// chunk layout per matrix-plane: [nt(8)][kc(4)][lane(64)] x 8 bf16, so a wave's
// B-frag load (ph[ci], ci=(nt*4+kc)*64+lane) is 1KB fully-coalesced.
__global__ void prep_weights_kernel(const float* __restrict__ W1, const float* __restrict__ W2,
                                    const float* __restrict__ Wo, const float* __restrict__ P1,
                                    const float* __restrict__ P2, const float* __restrict__ D1,
                                    const float* __restrict__ D2, unsigned short* __restrict__ prep) {
  int t = blockIdx.x * 256 + threadIdx.x;
  if (t >= 19 * 2048) return;
  int m = t >> 11;
  int rem = t & 2047;
  int nt = rem >> 8;
  int kc = (rem >> 6) & 3;
  int lane = rem & 63;
  const float* src;
  if (m < 5) src = W1 + (size_t)m * 16384;
  else if (m < 10) src = W2 + (size_t)(m - 5) * 16384;
  else if (m < 15) src = Wo + (size_t)(m - 10) * 16384;
  else if (m == 15) src = P1;
  else if (m == 16) src = P2;
  else if (m == 17) src = D1;
  else src = D2;
  int row = nt * 16 + (lane & 15);            // N index
  int k0 = kc * 32 + (lane >> 4) * 8;         // K index
  unsigned int hw[4], lw[4];
#pragma unroll
  for (int jj = 0; jj < 4; ++jj) {
    unsigned short h0, l0, h1, l1;
    bf16split_rne(src[row * D + k0 + 2 * jj], h0, l0);
    bf16split_rne(src[row * D + k0 + 2 * jj + 1], h1, l1);
    hw[jj] = (unsigned int)h0 | ((unsigned int)h1 << 16);
    lw[jj] = (unsigned int)l0 | ((unsigned int)l1 << 16);
  }
  size_t chunk = (size_t)((nt * 4 + kc) * 64 + lane);
  uint4v hv = {hw[0], hw[1], hw[2], hw[3]};
  uint4v lv = {lw[0], lw[1], lw[2], lw[3]};
  *(uint4v*)(prep + (size_t)(2 * m) * 16384 + chunk * 8) = hv;
  *(uint4v*)(prep + (size_t)(2 * m + 1) * 16384 + chunk * 8) = lv;
}

// ---------------- resMLP via MFMA: 4 waves/block, wave-private LDS, 0 barriers ----
__global__ __launch_bounds__(256) void resmlp_mfma(
    const float* __restrict__ xin, const unsigned short* __restrict__ prep,
    const float* __restrict__ b1b, const float* __restrict__ b2b,
    const float* __restrict__ act_a, const float* __restrict__ act_b,
    float* __restrict__ outbase, int branch_off, int n_atoms)
{
  __shared__ __align__(16) unsigned short shHiA[4][16 * D];
  __shared__ __align__(16) unsigned short shLoA[4][16 * D];
  const int lane = threadIdx.x & 63;
  const int wid = threadIdx.x >> 6;
  unsigned short* shHi = shHiA[wid];
  unsigned short* shLo = shLoA[wid];
  const int atom0 = (blockIdx.x * 4 + wid) * 16;
  const int br = blockIdx.y + branch_off;
  const float* b1 = b1b + br * D;
  const float* b2 = b2b + br * D;
  const float a0 = act_a[br * 3 + 0], g0 = act_b[br * 3 + 0];
  const float a1 = act_a[br * 3 + 1], g1 = act_b[br * 3 + 1];
  const float a2 = act_a[br * 3 + 2], g2 = act_b[br * 3 + 2];
  float* out = outbase + (size_t)blockIdx.y * n_atoms * D;
  const float* x0 = xin + (size_t)atom0 * D;

  stage16<true>(x0, lane, shHi, shLo, a0, g0);   // s0 = swish(x0)

  const int rl = lane & 15;
  const int rowq = (lane >> 4) * 4;
  short8v ah[4], al[4];
  f32x4 accs[8];

  // layer 1: h = s0 @ W1^T + b1; s1 = swish(h)
  load_afrags(shHi, lane, ah);
  load_afrags(shLo, lane, al);
  gemm16(ah, al, prep, br, lane, accs);
#pragma unroll
  for (int nt = 0; nt < 8; ++nt) {
    int col = nt * 16 + rl;
    float bv = b1[col];
#pragma unroll
    for (int r = 0; r < 4; ++r) {
      int row = rowq + r;
      float s = fast_swish(accs[nt][r] + bv, a1, g1);
      unsigned short h, l;
      bf16split_fast(s, h, l);
      int off = (col * 2) ^ ((row & 7) << 4);
      *(unsigned short*)((char*)(shHi + row * D) + off) = h;
      *(unsigned short*)((char*)(shLo + row * D) + off) = l;
    }
  }

  // layer 2: y = x0 + s1 @ W2^T + b2; s2 = swish(y)
  load_afrags(shHi, lane, ah);
  load_afrags(shLo, lane, al);
  gemm16(ah, al, prep, 5 + br, lane, accs);
#pragma unroll
  for (int nt = 0; nt < 8; ++nt) {
    int col = nt * 16 + rl;
    float bv = b2[col];
#pragma unroll
    for (int r = 0; r < 4; ++r) {
      int row = rowq + r;
      float y = x0[row * D + col] + accs[nt][r] + bv;   // residual re-read (L2)
      float s = fast_swish(y, a2, g2);
      unsigned short h, l;
      bf16split_fast(s, h, l);
      int off = (col * 2) ^ ((row & 7) << 4);
      *(unsigned short*)((char*)(shHi + row * D) + off) = h;
      *(unsigned short*)((char*)(shLo + row * D) + off) = l;
    }
  }

  // layer 3: out = s2 @ Wo^T
  load_afrags(shHi, lane, ah);
  load_afrags(shLo, lane, al);
  gemm16(ah, al, prep, 10 + br, lane, accs);
#pragma unroll
  for (int nt = 0; nt < 8; ++nt)
#pragma unroll
    for (int r = 0; r < 4; ++r)
      out[(size_t)(atom0 + rowq + r) * D + nt * 16 + rl] = accs[nt][r];
}

// ---------------- take_inner via MFMA: 4 waves/block, wave-private LDS ----------------
__global__ __launch_bounds__(256) void inner_mfma(
    const float* __restrict__ q1, const float* __restrict__ q2,
    const unsigned short* __restrict__ prep,
    float* __restrict__ pA, float* __restrict__ pB, int n_atoms)
{
  __shared__ __align__(16) unsigned short shHiA[4][16 * D];
  __shared__ __align__(16) unsigned short shLoA[4][16 * D];
  const int lane = threadIdx.x & 63;
  const int wid = threadIdx.x >> 6;
  unsigned short* shHi = shHiA[wid];
  unsigned short* shLo = shLoA[wid];
  const int atom0 = (blockIdx.x * 4 + wid) * 16;
  const int g = blockIdx.y;
  const size_t nd = (size_t)n_atoms * D;
  const int rl = lane & 15;
  const int rowq = (lane >> 4) * 4;
  f32x4 eacc[8];
#pragma unroll
  for (int nt = 0; nt < 8; ++nt) eacc[nt] = f32x4{0.f, 0.f, 0.f, 0.f};

  for (int pp = 0; pp < 2; ++pp) {
    const int part = g * 2 + pp;
    const float* qp = (part < 3) ? q1 + (size_t)part * nd : q2 + (size_t)(part - 3) * nd;
    const int m1 = (part < 3) ? 15 : 17;     // P1/P2 or D1/D2
    stage16<false>(qp + (size_t)atom0 * D, lane, shHi, shLo, 0.f, 0.f);
    short8v ah[4], al[4];
    load_afrags(shHi, lane, ah);
    load_afrags(shLo, lane, al);
    const short8v* p1h = (const short8v*)(prep + (size_t)(2 * m1) * 16384);
    const short8v* p1l = (const short8v*)(prep + (size_t)(2 * m1 + 1) * 16384);
    const short8v* p2h = (const short8v*)(prep + (size_t)(2 * m1 + 2) * 16384);
    const short8v* p2l = (const short8v*)(prep + (size_t)(2 * m1 + 3) * 16384);
#pragma unroll
    for (int nt = 0; nt < 8; ++nt) {
      f32x4 t1 = {0.f, 0.f, 0.f, 0.f}, t2 = {0.f, 0.f, 0.f, 0.f};
#pragma unroll
      for (int kc = 0; kc < 4; ++kc) {
        int ci = (nt * 4 + kc) * 64 + lane;
        short8v b1h = p1h[ci], b1l = p1l[ci];
        short8v b2h = p2h[ci], b2l = p2l[ci];
        t1 = __builtin_amdgcn_mfma_f32_16x16x32_bf16(al[kc], b1h, t1, 0, 0, 0);
        t1 = __builtin_amdgcn_mfma_f32_16x16x32_bf16(ah[kc], b1l, t1, 0, 0, 0);
        t1 = __builtin_amdgcn_mfma_f32_16x16x32_bf16(ah[kc], b1h, t1, 0, 0, 0);
        t2 = __builtin_amdgcn_mfma_f32_16x16x32_bf16(al[kc], b2h, t2, 0, 0, 0);
        t2 = __builtin_amdgcn_mfma_f32_16x16x32_bf16(ah[kc], b2l, t2, 0, 0, 0);
        t2 = __builtin_amdgcn_mfma_f32_16x16x32_bf16(ah[kc], b2h, t2, 0, 0, 0);
      }
      eacc[nt] += t1 * t2;
    }
  }
  float* outp = (g < 3) ? (pA + (size_t)g * nd) : pB;
#pragma unroll
  for (int nt = 0; nt < 8; ++nt)
#pragma unroll
    for (int r = 0; r < 4; ++r)
      outp[(size_t)(atom0 + rowq + r) * D + nt * 16 + rl] = eacc[nt][r];
}

// ---------------- per-edge geometry: rho[16], harmonics[8] ----------------
__global__ void edge_geom_kernel(const float* __restrict__ xyz,
                                 const int* __restrict__ nbrs,
                                 const float* __restrict__ gamma_p,
                                 float* __restrict__ rho_ws,
                                 float* __restrict__ y_ws, int n_edges)
{
  int e = blockIdx.x * 256 + threadIdx.x;
  if (e >= n_edges) return;
  int s = nbrs[2 * e], dd = nbrs[2 * e + 1];
  float rx = xyz[3 * dd + 0] - xyz[3 * s + 0];
  float ry = xyz[3 * dd + 1] - xyz[3 * s + 1];
  float rz = xyz[3 * dd + 2] - xyz[3 * s + 2];
  float r2 = rx * rx + ry * ry + rz * rz + 3e-15f;
  float r = sqrtf(r2);
  float inv = 1.0f / r;
  float ux = rx * inv, uy = ry * inv, uz = rz * inv;
  float gamma = gamma_p[0];
  float xv = __expf(-gamma * r);
  float omx = 1.0f - xv;
  float fcut = 0.0f;
  if (r < 5.0f) fcut = __expf(-r2 / (25.0f - r2));
  float xp[16], op[16];
  xp[0] = 1.f; op[0] = 1.f;
#pragma unroll
  for (int k = 1; k < 16; ++k) { xp[k] = xp[k - 1] * xv; op[k] = op[k - 1] * omx; }
  const float C[16] = {1.f, 15.f, 105.f, 455.f, 1365.f, 3003.f, 5005.f, 6435.f,
                       6435.f, 5005.f, 3003.f, 1365.f, 455.f, 105.f, 15.f, 1.f};
  float* rp = rho_ws + (size_t)e * 16;
#pragma unroll
  for (int k = 0; k < 16; ++k) rp[k] = C[k] * xp[k] * op[15 - k] * fcut;
  const float s3 = 1.7320508075688772f;
  float* yp = y_ws + (size_t)e * 8;
  yp[0] = uy; yp[1] = uz; yp[2] = ux;
  yp[3] = s3 * ux * uy; yp[4] = s3 * uy * uz; yp[5] = 0.5f * (3.f * uz * uz - 1.f);
  yp[6] = s3 * ux * uz; yp[7] = 0.5f * s3 * (ux * ux - uy * uy);
}

// ---------------- CSR build: histogram, scan, scatter ----------------
__global__ void hist_kernel(const int* __restrict__ nbrs, int* __restrict__ counts, int n_edges) {
  int e = blockIdx.x * 256 + threadIdx.x;
  if (e < n_edges) atomicAdd(&counts[nbrs[2 * e]], 1);
}

__global__ __launch_bounds__(1024) void scan_kernel(const int* __restrict__ counts,
                                                    int* __restrict__ offsets, int n) {
  __shared__ int part[1024];
  int tid = threadIdx.x;
  int base = tid * 16;
  int loc[16]; int s = 0;
#pragma unroll
  for (int i = 0; i < 16; ++i) {
    int c = (base + i < n) ? counts[base + i] : 0;
    loc[i] = c; s += c;
  }
  part[tid] = s;
  __syncthreads();
  for (int off = 1; off < 1024; off <<= 1) {
    int v = (tid >= off) ? part[tid - off] : 0;
    __syncthreads();
    part[tid] += v;
    __syncthreads();
  }
  int run = (tid == 0) ? 0 : part[tid - 1];
#pragma unroll
  for (int i = 0; i < 16; ++i) {
    if (base + i < n) offsets[base + i] = run;
    run += loc[i];
  }
}

__global__ void scatter_kernel(const int* __restrict__ nbrs, const int* __restrict__ offsets,
                               int* __restrict__ cursor, int* __restrict__ sorted, int n_edges) {
  int e = blockIdx.x * 256 + threadIdx.x;
  if (e < n_edges) {
    int s = nbrs[2 * e];
    int pos = offsets[s] + atomicAdd(&cursor[s], 1);
    sorted[pos] = e;
  }
}

// ---------------- per-atom aggregation (segment sum, no float atomics) ----------------
__global__ __launch_bounds__(128) void aggregate_kernel(
    const float* __restrict__ rho_ws, const float* __restrict__ y_ws,
    const int* __restrict__ nbrs, const int* __restrict__ offsets,
    const int* __restrict__ counts, const int* __restrict__ sorted,
    const float* __restrict__ feat1, const float* __restrict__ feat2,
    const float* __restrict__ feat3,
    const float* __restrict__ Gs, const float* __restrict__ Gp,
    const float* __restrict__ Gd,
    float* __restrict__ q0, float* __restrict__ q1, float* __restrict__ q2,
    int n_atoms)
{
  int n = blockIdx.x;
  int d = threadIdx.x;
  float gs[16], gp[16], gd[16];
#pragma unroll
  for (int c = 0; c < 4; ++c) {
    float4 v = *(const float4*)&Gs[d * 16 + 4 * c];
    gs[4 * c] = v.x; gs[4 * c + 1] = v.y; gs[4 * c + 2] = v.z; gs[4 * c + 3] = v.w;
    v = *(const float4*)&Gp[d * 16 + 4 * c];
    gp[4 * c] = v.x; gp[4 * c + 1] = v.y; gp[4 * c + 2] = v.z; gp[4 * c + 3] = v.w;
    v = *(const float4*)&Gd[d * 16 + 4 * c];
    gd[4 * c] = v.x; gd[4 * c + 1] = v.y; gd[4 * c + 2] = v.z; gd[4 * c + 3] = v.w;
  }
  float a0 = 0.f, a1[3] = {0.f, 0.f, 0.f}, a2[5] = {0.f, 0.f, 0.f, 0.f, 0.f};
  int off = offsets[n], cnt = counts[n];
  for (int i = 0; i < cnt; ++i) {
    int e = sorted[off + i];
    int dst = nbrs[2 * e + 1];
    const float4* rp = (const float4*)(rho_ws + (size_t)e * 16);
    float4 r0v = rp[0], r1v = rp[1], r2v = rp[2], r3v = rp[3];
    float rho[16] = {r0v.x, r0v.y, r0v.z, r0v.w, r1v.x, r1v.y, r1v.z, r1v.w,
                     r2v.x, r2v.y, r2v.z, r2v.w, r3v.x, r3v.y, r3v.z, r3v.w};
    const float4* ypv = (const float4*)(y_ws + (size_t)e * 8);
    float4 y0v = ypv[0], y1v = ypv[1];
    float g_s = 0.f, g_p = 0.f, g_d = 0.f;
#pragma unroll
    for (int k = 0; k < 16; ++k) {
      g_s += gs[k] * rho[k];
      g_p += gp[k] * rho[k];
      g_d += gd[k] * rho[k];
    }
    float f1 = feat1[(size_t)dst * D + d];
    float f2 = feat2[(size_t)dst * D + d];
    float f3 = feat3[(size_t)dst * D + d];
    a0 += f1 * g_s;
    float ap = f2 * g_p;
    a1[0] += ap * y0v.x; a1[1] += ap * y0v.y; a1[2] += ap * y0v.z;
    float ad = f3 * g_d;
    a2[0] += ad * y0v.w; a2[1] += ad * y1v.x; a2[2] += ad * y1v.y;
    a2[3] += ad * y1v.z; a2[4] += ad * y1v.w;
  }
  q0[(size_t)n * D + d] = a0;
#pragma unroll
  for (int m = 0; m < 3; ++m) q1[((size_t)m * n_atoms + n) * D + d] = a1[m];
#pragma unroll
  for (int m = 0; m < 5; ++m) q2[((size_t)m * n_atoms + n) * D + d] = a2[m];
}

// ---------------- assemble: inp = cterm + q0 + sum of 4 partials ----------------
__global__ void assemble_kernel(const float* __restrict__ cterm,
                                const float* __restrict__ q0,
                                const float* __restrict__ pA,
                                const float* __restrict__ pB,
                                float* __restrict__ inp, int nd4)
{
  int i = blockIdx.x * 256 + threadIdx.x;
  if (i >= nd4) return;
  const float4* c = (const float4*)cterm;
  const float4* z = (const float4*)q0;
  const float4* a = (const float4*)pA;
  const float4* b = (const float4*)pB;
  float4 v = c[i], zz = z[i];
  float4 a0 = a[i], a1 = a[i + (size_t)nd4], a2 = a[i + 2 * (size_t)nd4], bb = b[i];
  float4 r;
  r.x = v.x + zz.x + a0.x + a1.x + a2.x + bb.x;
  r.y = v.y + zz.y + a0.y + a1.y + a2.y + bb.y;
  r.z = v.z + zz.z + a0.z + a1.z + a2.z + bb.z;
  r.w = v.w + zz.w + a0.w + a1.w + a2.w + bb.w;
  ((float4*)inp)[i] = r;
}

extern "C" void kernel_launch(void* const* d_in, const int* in_sizes, int n_in,
                              void* d_out, int out_size, void* d_ws, size_t ws_size,
                              hipStream_t stream)
{
  const float* xyz     = (const float*)d_in[0];
  const float* x_tilde = (const float*)d_in[1];
  const int*   nbrs    = (const int*)d_in[2];
  const float* W1      = (const float*)d_in[3];
  const float* b1      = (const float*)d_in[4];
  const float* W2      = (const float*)d_in[5];
  const float* b2      = (const float*)d_in[6];
  const float* Wout    = (const float*)d_in[7];
  const float* act_a   = (const float*)d_in[8];
  const float* act_b   = (const float*)d_in[9];
  const float* Gs      = (const float*)d_in[10];
  const float* Gp      = (const float*)d_in[11];
  const float* Gd      = (const float*)d_in[12];
  const float* P1      = (const float*)d_in[13];
  const float* P2      = (const float*)d_in[14];
  const float* D1m     = (const float*)d_in[15];
  const float* D2m     = (const float*)d_in[16];
  const float* gamma   = (const float*)d_in[17];
  float* out = (float*)d_out;

  const int n_atoms = in_sizes[0] / 3;   // 16384
  const int n_edges = in_sizes[2] / 2;   // 100000

  // workspace layout (floats)
  float* ws = (float*)d_ws;
  size_t nd = (size_t)n_atoms * D;
  float* feats  = ws;                       // 4*nd: c_term, feat1..3
  float* q0     = feats + 4 * nd;           // nd
  float* q1     = q0 + nd;                  // 3*nd
  float* q2     = q1 + 3 * nd;              // 5*nd
  float* rho_ws = q2 + 5 * nd;              // E*16 (dead after aggregate -> partial B)
  float* y_ws   = rho_ws + (size_t)n_edges * 16;  // E*8
  float* inp    = y_ws + (size_t)n_edges * 8;     // nd
  int* counts  = (int*)(inp + nd);
  int* offsets = counts + n_atoms;
  int* cursor  = offsets + n_atoms;
  int* sorted  = cursor + n_atoms;          // E ints
  // prepped weights: 19 matrices x (hi,lo) x 16384 bf16 = 1.19 MB, 16B-aligned
  unsigned short* prep =
      (unsigned short*)(((uintptr_t)(sorted + n_edges) + 15) & ~(uintptr_t)15);

  // partials: reuse feat1..3 (dead after aggregate) for groups 0..2,
  // group 3 uses rho_ws+y_ws region (dead after aggregate; E*24 >= nd). OK.
  float* pA = feats + nd;
  float* pB = rho_ws;

  hipMemsetAsync(counts, 0, (size_t)n_atoms * sizeof(int), stream);
  hipMemsetAsync(cursor, 0, (size_t)n_atoms * sizeof(int), stream);

  dim3 blk(256);
  int eb = (n_edges + 255) / 256;

  prep_weights_kernel<<<(19 * 2048 + 255) / 256, blk, 0, stream>>>(
      W1, W2, Wout, P1, P2, D1m, D2m, prep);

  // branches 0..3 on x_tilde -> feats[branch]  (256 x 4 blocks, 4 waves each)
  resmlp_mfma<<<dim3(n_atoms / 64, 4), dim3(256), 0, stream>>>(
      x_tilde, prep, b1, b2, act_a, act_b, feats, 0, n_atoms);

  edge_geom_kernel<<<eb, blk, 0, stream>>>(xyz, nbrs, gamma, rho_ws, y_ws, n_edges);
  hist_kernel<<<eb, blk, 0, stream>>>(nbrs, counts, n_edges);
  scan_kernel<<<1, 1024, 0, stream>>>(counts, offsets, n_atoms);
  scatter_kernel<<<eb, blk, 0, stream>>>(nbrs, offsets, cursor, sorted, n_edges);

  aggregate_kernel<<<n_atoms, 128, 0, stream>>>(
      rho_ws, y_ws, nbrs, offsets, counts, sorted,
      feats + nd, feats + 2 * nd, feats + 3 * nd, Gs, Gp, Gd,
      q0, q1, q2, n_atoms);

  // take_inner split over 4 part-groups (256 x 4 blocks, 4 waves each)
  inner_mfma<<<dim3(n_atoms / 64, 4), dim3(256), 0, stream>>>(
      q1, q2, prep, pA, pB, n_atoms);

  assemble_kernel<<<(int)((nd / 4 + 255) / 256), blk, 0, stream>>>(
      feats, q0, pA, pB, inp, (int)(nd / 4));

  // branch 4 on inp -> out (256 blocks, 4 waves each)
  resmlp_mfma<<<dim3(n_atoms / 64, 1), dim3(256), 0, stream>>>(
      inp, prep, b1, b2, act_a, act_b, out, 4, n_atoms);
}

// Round 7
// 274.639 us; speedup vs baseline: 1.9660x; 1.2391x over previous
//
#include <hip/hip_runtime.h>
#include <math.h>

#define D 128

typedef __attribute__((ext_vector_type(8))) short short8v;   // 8 bf16 (4 VGPR)
typedef __attribute__((ext_vector_type(4))) float f32x4;      // MFMA acc
typedef __attribute__((ext_vector_type(4))) unsigned int uint4v;

// fast swish: a*x*sigmoid(b*x), exp2+rcp form (~6 VALU insts, rel err <2^-21)
__device__ __forceinline__ float fast_swish(float v, float a, float b) {
  float e = __builtin_amdgcn_exp2f(-1.4426950408889634f * (b * v));
  return a * v * __builtin_amdgcn_rcpf(1.0f + e);
}

// exact RNE split (prep only): v ~= hi + lo, err ~2^-18
__device__ __forceinline__ void bf16split_rne(float v, unsigned short& h, unsigned short& l) {
  unsigned int u = __float_as_uint(v);
  unsigned int rh = (u + 0x7FFFu + ((u >> 16) & 1u)) & 0xFFFF0000u;
  h = (unsigned short)(rh >> 16);
  float lf = v - __uint_as_float(rh);
  unsigned int u2 = __float_as_uint(lf);
  unsigned int rl = u2 + 0x7FFFu + ((u2 >> 16) & 1u);
  l = (unsigned short)(rl >> 16);
}

// fast split (hot path): truncate hi, RNE lo; reconstruction err ~2^-17
__device__ __forceinline__ void bf16split_fast(float v, unsigned short& h, unsigned short& l) {
  unsigned int u = __float_as_uint(v);
  h = (unsigned short)(u >> 16);
  float lf = v - __uint_as_float(u & 0xFFFF0000u);
  unsigned int u2 = __float_as_uint(lf);
  l = (unsigned short)((u2 + 0x7FFFu + ((u2 >> 16) & 1u)) >> 16);
}

// bf16x2-split 16x16x32 step: 3 MFMAs
__device__ __forceinline__ f32x4 mfma3(short8v ah, short8v al, short8v bh, short8v bl, f32x4 acc) {
  acc = __builtin_amdgcn_mfma_f32_16x16x32_bf16(al, bh, acc, 0, 0, 0);
  acc = __builtin_amdgcn_mfma_f32_16x16x32_bf16(ah, bl, acc, 0, 0, 0);
  acc = __builtin_amdgcn_mfma_f32_16x16x32_bf16(ah, bh, acc, 0, 0, 0);
  return acc;
}

// ---- stage a 16x128 f32 tile into XOR-swizzled hi/lo bf16 LDS (1 wave) ----
// swizzle: within-row byte offset ^= ((row&7)<<4)  (G4 fix for D=128 row-major)
template <bool SW>
__device__ __forceinline__ void stage16(const float* __restrict__ src, int lane,
                                        unsigned short* shHi, unsigned short* shLo,
                                        float a, float b) {
#pragma unroll
  for (int i = 0; i < 4; ++i) {
    int t = lane + 64 * i;
    int r = t >> 4, c = t & 15;          // row, 8-float chunk
    const float4 v0 = *(const float4*)(src + r * D + c * 8);
    const float4 v1 = *(const float4*)(src + r * D + c * 8 + 4);
    float vv[8] = {v0.x, v0.y, v0.z, v0.w, v1.x, v1.y, v1.z, v1.w};
    unsigned int hw[4], lw[4];
#pragma unroll
    for (int jj = 0; jj < 4; ++jj) {
      float x0 = SW ? fast_swish(vv[2 * jj], a, b) : vv[2 * jj];
      float x1 = SW ? fast_swish(vv[2 * jj + 1], a, b) : vv[2 * jj + 1];
      unsigned short h0, l0, h1, l1;
      bf16split_fast(x0, h0, l0);
      bf16split_fast(x1, h1, l1);
      hw[jj] = (unsigned int)h0 | ((unsigned int)h1 << 16);
      lw[jj] = (unsigned int)l0 | ((unsigned int)l1 << 16);
    }
    int off = (c * 16) ^ ((r & 7) << 4);
    uint4v hv = {hw[0], hw[1], hw[2], hw[3]};
    uint4v lv = {lw[0], lw[1], lw[2], lw[3]};
    *(uint4v*)((char*)(shHi + r * D) + off) = hv;
    *(uint4v*)((char*)(shLo + r * D) + off) = lv;
  }
}

// ---- prep: 19 [128x128] f32 matrices -> fragment-major bf16 hi/lo planes ----
// m: 0-4 W1[br], 5-9 W2[br], 10-14 Wout[br], 15 P1, 16 P2, 17 D1, 18 D2
// chunk layout per matrix-plane: [nt(8)][kc(4)][lane(64)] x 8 bf16, so a wave's
// B-frag load (chunk ci=(nt*4+kc)*64+lane) is 1KB fully-coalesced.
__global__ void prep_weights_kernel(const float* __restrict__ W1, const float* __restrict__ W2,
                                    const float* __restrict__ Wo, const float* __restrict__ P1,
                                    const float* __restrict__ P2, const float* __restrict__ D1,
                                    const float* __restrict__ D2, unsigned short* __restrict__ prep) {
  int t = blockIdx.x * 256 + threadIdx.x;
  if (t >= 19 * 2048) return;
  int m = t >> 11;
  int rem = t & 2047;
  int nt = rem >> 8;
  int kc = (rem >> 6) & 3;
  int lane = rem & 63;
  const float* src;
  if (m < 5) src = W1 + (size_t)m * 16384;
  else if (m < 10) src = W2 + (size_t)(m - 5) * 16384;
  else if (m < 15) src = Wo + (size_t)(m - 10) * 16384;
  else if (m == 15) src = P1;
  else if (m == 16) src = P2;
  else if (m == 17) src = D1;
  else src = D2;
  int row = nt * 16 + (lane & 15);            // N index
  int k0 = kc * 32 + (lane >> 4) * 8;         // K index
  unsigned int hw[4], lw[4];
#pragma unroll
  for (int jj = 0; jj < 4; ++jj) {
    unsigned short h0, l0, h1, l1;
    bf16split_rne(src[row * D + k0 + 2 * jj], h0, l0);
    bf16split_rne(src[row * D + k0 + 2 * jj + 1], h1, l1);
    hw[jj] = (unsigned int)h0 | ((unsigned int)h1 << 16);
    lw[jj] = (unsigned int)l0 | ((unsigned int)l1 << 16);
  }
  size_t chunk = (size_t)((nt * 4 + kc) * 64 + lane);
  uint4v hv = {hw[0], hw[1], hw[2], hw[3]};
  uint4v lv = {lw[0], lw[1], lw[2], lw[3]};
  *(uint4v*)(prep + (size_t)(2 * m) * 16384 + chunk * 8) = hv;
  *(uint4v*)(prep + (size_t)(2 * m + 1) * 16384 + chunk * 8) = lv;
}

// ---------------- resMLP via MFMA: 64-atom block tile, N split across 4 waves ----
// wave w computes output cols [32w, 32w+32) for all 64 rows: each B-frag reused
// 4x (vs 1x at M=16) -> B-stream need ~34 B/cyc/CU, under L2 BW.
__global__ __launch_bounds__(256) void resmlp_mfma(
    const float* __restrict__ xin, const unsigned short* __restrict__ prep,
    const float* __restrict__ b1b, const float* __restrict__ b2b,
    const float* __restrict__ act_a, const float* __restrict__ act_b,
    float* __restrict__ outbase, int branch_off, int n_atoms)
{
  __shared__ __align__(16) unsigned short shHi[64 * D];
  __shared__ __align__(16) unsigned short shLo[64 * D];
  const int lane = threadIdx.x & 63;
  const int wid = threadIdx.x >> 6;
  const int atom0 = blockIdx.x * 64;
  const int br = blockIdx.y + branch_off;
  const float* b1 = b1b + br * D;
  const float* b2 = b2b + br * D;
  const float a0 = act_a[br * 3 + 0], g0 = act_b[br * 3 + 0];
  const float a1 = act_a[br * 3 + 1], g1 = act_b[br * 3 + 1];
  const float a2 = act_a[br * 3 + 2], g2 = act_b[br * 3 + 2];
  float* out = outbase + (size_t)blockIdx.y * n_atoms * D;
  const float* x0 = xin + (size_t)atom0 * D;

  // cooperative stage: wave w stages rows [16w,16w+16) with swish applied
  stage16<true>(x0 + wid * 16 * D, lane, shHi + wid * 16 * D, shLo + wid * 16 * D, a0, g0);
  __syncthreads();

  const int rl = lane & 15;
  const int q = lane >> 4;
  const int rowq = q * 4;
  const int nt0 = wid * 2;

  f32x4 acc[4][2];

#define GEMM_LAYER(mat)                                                        \
  do {                                                                         \
    const unsigned short* ph = prep + (size_t)(2 * (mat)) * 16384;             \
    const unsigned short* pl = prep + (size_t)(2 * (mat) + 1) * 16384;         \
    _Pragma("unroll") for (int mt = 0; mt < 4; ++mt)                           \
        _Pragma("unroll") for (int j = 0; j < 2; ++j)                          \
            acc[mt][j] = f32x4{0.f, 0.f, 0.f, 0.f};                            \
    _Pragma("unroll") for (int kc = 0; kc < 4; ++kc) {                         \
      int ci0 = (nt0 * 4 + kc) * 64 + lane;                                    \
      int ci1 = ((nt0 + 1) * 4 + kc) * 64 + lane;                              \
      short8v bh0 = *(const short8v*)(ph + (size_t)ci0 * 8);                   \
      short8v bl0 = *(const short8v*)(pl + (size_t)ci0 * 8);                   \
      short8v bh1 = *(const short8v*)(ph + (size_t)ci1 * 8);                   \
      short8v bl1 = *(const short8v*)(pl + (size_t)ci1 * 8);                   \
      int aoff = (kc * 64 + q * 16) ^ ((rl & 7) << 4);                         \
      _Pragma("unroll") for (int mt = 0; mt < 4; ++mt) {                       \
        short8v ah = *(const short8v*)((const char*)(shHi + (mt * 16 + rl) * D) + aoff); \
        short8v al = *(const short8v*)((const char*)(shLo + (mt * 16 + rl) * D) + aoff); \
        acc[mt][0] = mfma3(ah, al, bh0, bl0, acc[mt][0]);                      \
        acc[mt][1] = mfma3(ah, al, bh1, bl1, acc[mt][1]);                      \
      }                                                                        \
    }                                                                          \
  } while (0)

  // layer 1: h = s0 @ W1^T + b1; s1 = swish(h)
  GEMM_LAYER(br);
  __syncthreads();   // all reads of s0 done before overwrite
#pragma unroll
  for (int j = 0; j < 2; ++j) {
    int col = (nt0 + j) * 16 + rl;
    float bv = b1[col];
#pragma unroll
    for (int mt = 0; mt < 4; ++mt)
#pragma unroll
      for (int r = 0; r < 4; ++r) {
        int row = mt * 16 + rowq + r;
        float s = fast_swish(acc[mt][j][r] + bv, a1, g1);
        unsigned short h, l;
        bf16split_fast(s, h, l);
        int off = (col * 2) ^ ((row & 7) << 4);
        *(unsigned short*)((char*)(shHi + row * D) + off) = h;
        *(unsigned short*)((char*)(shLo + row * D) + off) = l;
      }
  }
  __syncthreads();

  // layer 2: y = x0 + s1 @ W2^T + b2; s2 = swish(y)
  GEMM_LAYER(5 + br);
  __syncthreads();
#pragma unroll
  for (int j = 0; j < 2; ++j) {
    int col = (nt0 + j) * 16 + rl;
    float bv = b2[col];
#pragma unroll
    for (int mt = 0; mt < 4; ++mt)
#pragma unroll
      for (int r = 0; r < 4; ++r) {
        int row = mt * 16 + rowq + r;
        float y = x0[row * D + col] + acc[mt][j][r] + bv;   // residual (L1/L2 re-read)
        float s = fast_swish(y, a2, g2);
        unsigned short h, l;
        bf16split_fast(s, h, l);
        int off = (col * 2) ^ ((row & 7) << 4);
        *(unsigned short*)((char*)(shHi + row * D) + off) = h;
        *(unsigned short*)((char*)(shLo + row * D) + off) = l;
      }
  }
  __syncthreads();

  // layer 3: out = s2 @ Wo^T
  GEMM_LAYER(10 + br);
#pragma unroll
  for (int j = 0; j < 2; ++j)
#pragma unroll
    for (int mt = 0; mt < 4; ++mt)
#pragma unroll
      for (int r = 0; r < 4; ++r)
        out[(size_t)(atom0 + mt * 16 + rowq + r) * D + (nt0 + j) * 16 + rl] = acc[mt][j][r];
#undef GEMM_LAYER
}

// ---------------- take_inner via MFMA: 64-atom block tile, N split across waves ----
__global__ __launch_bounds__(256) void inner_mfma(
    const float* __restrict__ q1, const float* __restrict__ q2,
    const unsigned short* __restrict__ prep,
    float* __restrict__ pA, float* __restrict__ pB, int n_atoms)
{
  __shared__ __align__(16) unsigned short shHi[64 * D];
  __shared__ __align__(16) unsigned short shLo[64 * D];
  const int lane = threadIdx.x & 63;
  const int wid = threadIdx.x >> 6;
  const int atom0 = blockIdx.x * 64;
  const int g = blockIdx.y;
  const size_t nd = (size_t)n_atoms * D;
  const int rl = lane & 15;
  const int q = lane >> 4;
  const int rowq = q * 4;
  const int nt0 = wid * 2;

  f32x4 eacc[4][2];
#pragma unroll
  for (int mt = 0; mt < 4; ++mt)
#pragma unroll
    for (int j = 0; j < 2; ++j) eacc[mt][j] = f32x4{0.f, 0.f, 0.f, 0.f};

  for (int pp = 0; pp < 2; ++pp) {
    const int part = g * 2 + pp;
    const float* qp = (part < 3) ? q1 + (size_t)part * nd : q2 + (size_t)(part - 3) * nd;
    const int m1 = (part < 3) ? 15 : 17;     // P1/P2 or D1/D2
    if (pp) __syncthreads();                 // prior part's reads done before restage
    stage16<false>(qp + (size_t)atom0 * D + wid * 16 * D, lane,
                   shHi + wid * 16 * D, shLo + wid * 16 * D, 0.f, 0.f);
    __syncthreads();
    const unsigned short* p1h = prep + (size_t)(2 * m1) * 16384;
    const unsigned short* p1l = prep + (size_t)(2 * m1 + 1) * 16384;
    const unsigned short* p2h = prep + (size_t)(2 * m1 + 2) * 16384;
    const unsigned short* p2l = prep + (size_t)(2 * m1 + 3) * 16384;
#pragma unroll
    for (int j = 0; j < 2; ++j) {
      f32x4 t1[4], t2[4];
#pragma unroll
      for (int mt = 0; mt < 4; ++mt) {
        t1[mt] = f32x4{0.f, 0.f, 0.f, 0.f};
        t2[mt] = f32x4{0.f, 0.f, 0.f, 0.f};
      }
#pragma unroll
      for (int kc = 0; kc < 4; ++kc) {
        int ci = ((nt0 + j) * 4 + kc) * 64 + lane;
        short8v b1h = *(const short8v*)(p1h + (size_t)ci * 8);
        short8v b1l = *(const short8v*)(p1l + (size_t)ci * 8);
        short8v b2h = *(const short8v*)(p2h + (size_t)ci * 8);
        short8v b2l = *(const short8v*)(p2l + (size_t)ci * 8);
        int aoff = (kc * 64 + q * 16) ^ ((rl & 7) << 4);
#pragma unroll
        for (int mt = 0; mt < 4; ++mt) {
          short8v ah = *(const short8v*)((const char*)(shHi + (mt * 16 + rl) * D) + aoff);
          short8v al = *(const short8v*)((const char*)(shLo + (mt * 16 + rl) * D) + aoff);
          t1[mt] = mfma3(ah, al, b1h, b1l, t1[mt]);
          t2[mt] = mfma3(ah, al, b2h, b2l, t2[mt]);
        }
      }
#pragma unroll
      for (int mt = 0; mt < 4; ++mt) eacc[mt][j] += t1[mt] * t2[mt];
    }
  }

  float* outp = (g < 3) ? (pA + (size_t)g * nd) : pB;
#pragma unroll
  for (int j = 0; j < 2; ++j)
#pragma unroll
    for (int mt = 0; mt < 4; ++mt)
#pragma unroll
      for (int r = 0; r < 4; ++r)
        outp[(size_t)(atom0 + mt * 16 + rowq + r) * D + (nt0 + j) * 16 + rl] = eacc[mt][j][r];
}

// ---------------- per-edge geometry: rho[16], harmonics[8] ----------------
__global__ void edge_geom_kernel(const float* __restrict__ xyz,
                                 const int* __restrict__ nbrs,
                                 const float* __restrict__ gamma_p,
                                 float* __restrict__ rho_ws,
                                 float* __restrict__ y_ws, int n_edges)
{
  int e = blockIdx.x * 256 + threadIdx.x;
  if (e >= n_edges) return;
  int s = nbrs[2 * e], dd = nbrs[2 * e + 1];
  float rx = xyz[3 * dd + 0] - xyz[3 * s + 0];
  float ry = xyz[3 * dd + 1] - xyz[3 * s + 1];
  float rz = xyz[3 * dd + 2] - xyz[3 * s + 2];
  float r2 = rx * rx + ry * ry + rz * rz + 3e-15f;
  float r = sqrtf(r2);
  float inv = 1.0f / r;
  float ux = rx * inv, uy = ry * inv, uz = rz * inv;
  float gamma = gamma_p[0];
  float xv = __expf(-gamma * r);
  float omx = 1.0f - xv;
  float fcut = 0.0f;
  if (r < 5.0f) fcut = __expf(-r2 / (25.0f - r2));
  float xp[16], op[16];
  xp[0] = 1.f; op[0] = 1.f;
#pragma unroll
  for (int k = 1; k < 16; ++k) { xp[k] = xp[k - 1] * xv; op[k] = op[k - 1] * omx; }
  const float C[16] = {1.f, 15.f, 105.f, 455.f, 1365.f, 3003.f, 5005.f, 6435.f,
                       6435.f, 5005.f, 3003.f, 1365.f, 455.f, 105.f, 15.f, 1.f};
  float* rp = rho_ws + (size_t)e * 16;
#pragma unroll
  for (int k = 0; k < 16; ++k) rp[k] = C[k] * xp[k] * op[15 - k] * fcut;
  const float s3 = 1.7320508075688772f;
  float* yp = y_ws + (size_t)e * 8;
  yp[0] = uy; yp[1] = uz; yp[2] = ux;
  yp[3] = s3 * ux * uy; yp[4] = s3 * uy * uz; yp[5] = 0.5f * (3.f * uz * uz - 1.f);
  yp[6] = s3 * ux * uz; yp[7] = 0.5f * s3 * (ux * ux - uy * uy);
}

// ---------------- CSR build: histogram, scan, scatter ----------------
__global__ void hist_kernel(const int* __restrict__ nbrs, int* __restrict__ counts, int n_edges) {
  int e = blockIdx.x * 256 + threadIdx.x;
  if (e < n_edges) atomicAdd(&counts[nbrs[2 * e]], 1);
}

__global__ __launch_bounds__(1024) void scan_kernel(const int* __restrict__ counts,
                                                    int* __restrict__ offsets, int n) {
  __shared__ int part[1024];
  int tid = threadIdx.x;
  int base = tid * 16;
  int loc[16]; int s = 0;
#pragma unroll
  for (int i = 0; i < 16; ++i) {
    int c = (base + i < n) ? counts[base + i] : 0;
    loc[i] = c; s += c;
  }
  part[tid] = s;
  __syncthreads();
  for (int off = 1; off < 1024; off <<= 1) {
    int v = (tid >= off) ? part[tid - off] : 0;
    __syncthreads();
    part[tid] += v;
    __syncthreads();
  }
  int run = (tid == 0) ? 0 : part[tid - 1];
#pragma unroll
  for (int i = 0; i < 16; ++i) {
    if (base + i < n) offsets[base + i] = run;
    run += loc[i];
  }
}

__global__ void scatter_kernel(const int* __restrict__ nbrs, const int* __restrict__ offsets,
                               int* __restrict__ cursor, int* __restrict__ sorted, int n_edges) {
  int e = blockIdx.x * 256 + threadIdx.x;
  if (e < n_edges) {
    int s = nbrs[2 * e];
    int pos = offsets[s] + atomicAdd(&cursor[s], 1);
    sorted[pos] = e;
  }
}

// ---------------- per-atom aggregation (segment sum, no float atomics) ----------------
__global__ __launch_bounds__(128) void aggregate_kernel(
    const float* __restrict__ rho_ws, const float* __restrict__ y_ws,
    const int* __restrict__ nbrs, const int* __restrict__ offsets,
    const int* __restrict__ counts, const int* __restrict__ sorted,
    const float* __restrict__ feat1, const float* __restrict__ feat2,
    const float* __restrict__ feat3,
    const float* __restrict__ Gs, const float* __restrict__ Gp,
    const float* __restrict__ Gd,
    float* __restrict__ q0, float* __restrict__ q1, float* __restrict__ q2,
    int n_atoms)
{
  int n = blockIdx.x;
  int d = threadIdx.x;
  float gs[16], gp[16], gd[16];
#pragma unroll
  for (int c = 0; c < 4; ++c) {
    float4 v = *(const float4*)&Gs[d * 16 + 4 * c];
    gs[4 * c] = v.x; gs[4 * c + 1] = v.y; gs[4 * c + 2] = v.z; gs[4 * c + 3] = v.w;
    v = *(const float4*)&Gp[d * 16 + 4 * c];
    gp[4 * c] = v.x; gp[4 * c + 1] = v.y; gp[4 * c + 2] = v.z; gp[4 * c + 3] = v.w;
    v = *(const float4*)&Gd[d * 16 + 4 * c];
    gd[4 * c] = v.x; gd[4 * c + 1] = v.y; gd[4 * c + 2] = v.z; gd[4 * c + 3] = v.w;
  }
  float a0 = 0.f, a1[3] = {0.f, 0.f, 0.f}, a2[5] = {0.f, 0.f, 0.f, 0.f, 0.f};
  int off = offsets[n], cnt = counts[n];
  for (int i = 0; i < cnt; ++i) {
    int e = sorted[off + i];
    int dst = nbrs[2 * e + 1];
    const float4* rp = (const float4*)(rho_ws + (size_t)e * 16);
    float4 r0v = rp[0], r1v = rp[1], r2v = rp[2], r3v = rp[3];
    float rho[16] = {r0v.x, r0v.y, r0v.z, r0v.w, r1v.x, r1v.y, r1v.z, r1v.w,
                     r2v.x, r2v.y, r2v.z, r2v.w, r3v.x, r3v.y, r3v.z, r3v.w};
    const float4* ypv = (const float4*)(y_ws + (size_t)e * 8);
    float4 y0v = ypv[0], y1v = ypv[1];
    float g_s = 0.f, g_p = 0.f, g_d = 0.f;
#pragma unroll
    for (int k = 0; k < 16; ++k) {
      g_s += gs[k] * rho[k];
      g_p += gp[k] * rho[k];
      g_d += gd[k] * rho[k];
    }
    float f1 = feat1[(size_t)dst * D + d];
    float f2 = feat2[(size_t)dst * D + d];
    float f3 = feat3[(size_t)dst * D + d];
    a0 += f1 * g_s;
    float ap = f2 * g_p;
    a1[0] += ap * y0v.x; a1[1] += ap * y0v.y; a1[2] += ap * y0v.z;
    float ad = f3 * g_d;
    a2[0] += ad * y0v.w; a2[1] += ad * y1v.x; a2[2] += ad * y1v.y;
    a2[3] += ad * y1v.z; a2[4] += ad * y1v.w;
  }
  q0[(size_t)n * D + d] = a0;
#pragma unroll
  for (int m = 0; m < 3; ++m) q1[((size_t)m * n_atoms + n) * D + d] = a1[m];
#pragma unroll
  for (int m = 0; m < 5; ++m) q2[((size_t)m * n_atoms + n) * D + d] = a2[m];
}

// ---------------- assemble: inp = cterm + q0 + sum of 4 partials ----------------
__global__ void assemble_kernel(const float* __restrict__ cterm,
                                const float* __restrict__ q0,
                                const float* __restrict__ pA,
                                const float* __restrict__ pB,
                                float* __restrict__ inp, int nd4)
{
  int i = blockIdx.x * 256 + threadIdx.x;
  if (i >= nd4) return;
  const float4* c = (const float4*)cterm;
  const float4* z = (const float4*)q0;
  const float4* a = (const float4*)pA;
  const float4* b = (const float4*)pB;
  float4 v = c[i], zz = z[i];
  float4 a0 = a[i], a1 = a[i + (size_t)nd4], a2 = a[i + 2 * (size_t)nd4], bb = b[i];
  float4 r;
  r.x = v.x + zz.x + a0.x + a1.x + a2.x + bb.x;
  r.y = v.y + zz.y + a0.y + a1.y + a2.y + bb.y;
  r.z = v.z + zz.z + a0.z + a1.z + a2.z + bb.z;
  r.w = v.w + zz.w + a0.w + a1.w + a2.w + bb.w;
  ((float4*)inp)[i] = r;
}

extern "C" void kernel_launch(void* const* d_in, const int* in_sizes, int n_in,
                              void* d_out, int out_size, void* d_ws, size_t ws_size,
                              hipStream_t stream)
{
  const float* xyz     = (const float*)d_in[0];
  const float* x_tilde = (const float*)d_in[1];
  const int*   nbrs    = (const int*)d_in[2];
  const float* W1      = (const float*)d_in[3];
  const float* b1      = (const float*)d_in[4];
  const float* W2      = (const float*)d_in[5];
  const float* b2      = (const float*)d_in[6];
  const float* Wout    = (const float*)d_in[7];
  const float* act_a   = (const float*)d_in[8];
  const float* act_b   = (const float*)d_in[9];
  const float* Gs      = (const float*)d_in[10];
  const float* Gp      = (const float*)d_in[11];
  const float* Gd      = (const float*)d_in[12];
  const float* P1      = (const float*)d_in[13];
  const float* P2      = (const float*)d_in[14];
  const float* D1m     = (const float*)d_in[15];
  const float* D2m     = (const float*)d_in[16];
  const float* gamma   = (const float*)d_in[17];
  float* out = (float*)d_out;

  const int n_atoms = in_sizes[0] / 3;   // 16384
  const int n_edges = in_sizes[2] / 2;   // 100000

  // workspace layout (floats)
  float* ws = (float*)d_ws;
  size_t nd = (size_t)n_atoms * D;
  float* feats  = ws;                       // 4*nd: c_term, feat1..3
  float* q0     = feats + 4 * nd;           // nd
  float* q1     = q0 + nd;                  // 3*nd
  float* q2     = q1 + 3 * nd;              // 5*nd
  float* rho_ws = q2 + 5 * nd;              // E*16 (dead after aggregate -> partial B)
  float* y_ws   = rho_ws + (size_t)n_edges * 16;  // E*8
  float* inp    = y_ws + (size_t)n_edges * 8;     // nd
  int* counts  = (int*)(inp + nd);
  int* offsets = counts + n_atoms;
  int* cursor  = offsets + n_atoms;
  int* sorted  = cursor + n_atoms;          // E ints
  // prepped weights: 19 matrices x (hi,lo) x 16384 bf16 = 1.19 MB, 16B-aligned
  unsigned short* prep =
      (unsigned short*)(((uintptr_t)(sorted + n_edges) + 15) & ~(uintptr_t)15);

  // partials: reuse feat1..3 (dead after aggregate) for groups 0..2,
  // group 3 uses rho_ws+y_ws region (dead after aggregate; E*24 >= nd). OK.
  float* pA = feats + nd;
  float* pB = rho_ws;

  hipMemsetAsync(counts, 0, (size_t)n_atoms * sizeof(int), stream);
  hipMemsetAsync(cursor, 0, (size_t)n_atoms * sizeof(int), stream);

  dim3 blk(256);
  int eb = (n_edges + 255) / 256;

  prep_weights_kernel<<<(19 * 2048 + 255) / 256, blk, 0, stream>>>(
      W1, W2, Wout, P1, P2, D1m, D2m, prep);

  // branches 0..3 on x_tilde -> feats[branch]  (256 x 4 blocks, 64-atom tiles)
  resmlp_mfma<<<dim3(n_atoms / 64, 4), dim3(256), 0, stream>>>(
      x_tilde, prep, b1, b2, act_a, act_b, feats, 0, n_atoms);

  edge_geom_kernel<<<eb, blk, 0, stream>>>(xyz, nbrs, gamma, rho_ws, y_ws, n_edges);
  hist_kernel<<<eb, blk, 0, stream>>>(nbrs, counts, n_edges);
  scan_kernel<<<1, 1024, 0, stream>>>(counts, offsets, n_atoms);
  scatter_kernel<<<eb, blk, 0, stream>>>(nbrs, offsets, cursor, sorted, n_edges);

  aggregate_kernel<<<n_atoms, 128, 0, stream>>>(
      rho_ws, y_ws, nbrs, offsets, counts, sorted,
      feats + nd, feats + 2 * nd, feats + 3 * nd, Gs, Gp, Gd,
      q0, q1, q2, n_atoms);

  // take_inner split over 4 part-groups (256 x 4 blocks, 64-atom tiles)
  inner_mfma<<<dim3(n_atoms / 64, 4), dim3(256), 0, stream>>>(
      q1, q2, prep, pA, pB, n_atoms);

  assemble_kernel<<<(int)((nd / 4 + 255) / 256), blk, 0, stream>>>(
      feats, q0, pA, pB, inp, (int)(nd / 4));

  // branch 4 on inp -> out (256 blocks, 64-atom tiles)
  resmlp_mfma<<<dim3(n_atoms / 64, 1), dim3(256), 0, stream>>>(
      inp, prep, b1, b2, act_a, act_b, out, 4, n_atoms);
}